// Round 1
// baseline (964.664 us; speedup 1.0000x reference)
//
#include <hip/hip_runtime.h>
#include <cmath>

// ============================================================================
// AutoregressiveGroupQuerySelfAttention  (B=2, S=2048, H=2048, nH=16, D=128)
//
// Round 1: correctness-first baseline.
//  - Logit path (x, Wq, Wk, QK^T) in split precision: bf16 hi + bf16 lo,
//    3-term MFMA (hh+hl+lh). Reason: reference multiplies scores by sqrt(D)
//    => logits sigma ~128, near-argmax softmax; plain bf16 gives ~0.5 logit
//    error and fails the 0.106 absmax threshold on near-tie rows.
//  - Smooth path (V, P*V, ctx*Wo^T) in plain bf16.
//  - Workspace requirement: ~203 MB.
// ============================================================================

typedef unsigned short u16;
typedef __attribute__((ext_vector_type(4))) float  f32x4;
typedef __attribute__((ext_vector_type(4))) float  float4v;
typedef __attribute__((ext_vector_type(4))) unsigned short u16x4;
typedef __attribute__((ext_vector_type(8))) unsigned short u16x8;
typedef __attribute__((ext_vector_type(8))) short s16x8;

__device__ __forceinline__ u16 f2bf(float f) {
  unsigned u = __float_as_uint(f);
  u += 0x7FFFu + ((u >> 16) & 1u);            // RNE; inputs are finite
  return (u16)(u >> 16);
}
__device__ __forceinline__ float bf2f(u16 h) {
  return __uint_as_float(((unsigned)h) << 16);
}
__device__ __forceinline__ f32x4 MFMA(s16x8 a, s16x8 b, f32x4 c) {
  return __builtin_amdgcn_mfma_f32_16x16x32_bf16(a, b, c, 0, 0, 0);
}

// ---------------------------------------------------------------------------
// fp32 -> bf16 hi (+ optional lo residual).  n4 = element count / 4.
// ---------------------------------------------------------------------------
__global__ void split_bf16(const float* __restrict__ src, u16* __restrict__ hi,
                           u16* __restrict__ lo, int n4) {
  int i = blockIdx.x * 256 + threadIdx.x;
  if (i >= n4) return;
  float4v v = ((const float4v*)src)[i];
  u16x4 hv, lv;
#pragma unroll
  for (int j = 0; j < 4; ++j) {
    float f = v[j];
    u16 h = f2bf(f);
    hv[j] = h;
    lv[j] = f2bf(f - bf2f(h));
  }
  ((u16x4*)hi)[i] = hv;
  if (lo) ((u16x4*)lo)[i] = lv;
}

// ---------------------------------------------------------------------------
// RoPE tables in fp64 (matches either fp32 or fp64 numpy reference to ~6e-8).
// idx = s*64 + i,  i in [0,64)
// ---------------------------------------------------------------------------
__global__ void rope_tab(float* __restrict__ cosT, float* __restrict__ sinT) {
  int idx = blockIdx.x * 256 + threadIdx.x;   // 2048*64
  int i = idx & 63, s = idx >> 6;
  double invf = pow(10000.0, -(double)i / 64.0);
  double ang = (double)s * invf;
  cosT[idx] = (float)cos(ang);
  sinT[idx] = (float)sin(ang);
}

// ---------------------------------------------------------------------------
// In-place RoPE on a bf16 hi/lo pair array laid out (B*S, H=2048).
// One thread per (row, head, i<64) rotation pair.
// ---------------------------------------------------------------------------
__global__ void rope_apply(u16* __restrict__ Xh, u16* __restrict__ Xl,
                           const float* __restrict__ cosT,
                           const float* __restrict__ sinT) {
  int idx = blockIdx.x * 256 + threadIdx.x;   // 2*2048*16*64 = 4,194,304
  int i = idx & 63;
  int hh = (idx >> 6) & 15;
  int row = idx >> 10;                        // b*2048 + s
  int s = row & 2047;
  size_t base = (size_t)row * 2048 + hh * 128;
  size_t c1 = base + i, c2 = c1 + 64;
  float x1 = bf2f(Xh[c1]) + bf2f(Xl[c1]);
  float x2 = bf2f(Xh[c2]) + bf2f(Xl[c2]);
  float cs = cosT[s * 64 + i], sn = sinT[s * 64 + i];
  float o1 = x1 * cs - x2 * sn;
  float o2 = x2 * cs + x1 * sn;
  u16 h1 = f2bf(o1); Xh[c1] = h1; Xl[c1] = f2bf(o1 - bf2f(h1));
  u16 h2 = f2bf(o2); Xh[c2] = h2; Xl[c2] = f2bf(o2 - bf2f(h2));
}

// ---------------------------------------------------------------------------
// V (B,S,16*128) bf16  ->  Vt (B,16,128,S) bf16   (per-head transpose)
// grid: x = (s_tile*4 + d_tile) [256], y = head, z = batch;  32x32 tiles.
// ---------------------------------------------------------------------------
__global__ void transpose_v(const u16* __restrict__ Vb, u16* __restrict__ Vt) {
  __shared__ u16 tile[32][40];
  int st = blockIdx.x >> 2;
  int dt = blockIdx.x & 3;
  int h = blockIdx.y, b = blockIdx.z;
  int t = threadIdx.x;
  int r = t >> 3, c = (t & 7) * 4;
  const u16* src = Vb + ((size_t)(b * 2048 + st * 32 + r)) * 2048 + h * 128 + dt * 32 + c;
  *(u16x4*)&tile[r][c] = *(const u16x4*)src;
  __syncthreads();
  u16x4 o;
#pragma unroll
  for (int j = 0; j < 4; ++j) o[j] = tile[c + j][r];
  u16* dst = Vt + ((size_t)((b * 16 + h) * 128 + dt * 32 + r)) * 2048 + st * 32 + c;
  *(u16x4*)dst = o;
}

// ---------------------------------------------------------------------------
// GEMM  C(MxN) = A(MxK) * B(NxK)^T, bf16 inputs, fp32 accumulate.
// NTERM==3: A,B given as hi/lo pairs, compute hh+hl+lh (split precision).
// OMODE: 0 = fp32 out, 1 = bf16 hi/lo out, 2 = bf16 out.
// 128x128 tile, BK=32, 4 waves each 64x64 (4x4 of 16x16x32 MFMA).
// LDS rows padded to 40 elems (80B) -> 16B-aligned b128, 2-way banks (free).
// ---------------------------------------------------------------------------
template <int NTERM, int OMODE>
__global__ __launch_bounds__(256)
void gemm_bt(const u16* __restrict__ Ah, const u16* __restrict__ Al,
             const u16* __restrict__ Bh, const u16* __restrict__ Bl,
             float* __restrict__ Cf, u16* __restrict__ Ch, u16* __restrict__ Cl,
             int M, int N, int K) {
  constexpr int LD = 40;
  constexpr int LOFF = 128 * LD;
  __shared__ u16 As[(NTERM == 3 ? 2 : 1) * 128 * LD];
  __shared__ u16 Bs[(NTERM == 3 ? 2 : 1) * 128 * LD];
  const int bn = blockIdx.x, bm = blockIdx.y;
  const int t = threadIdx.x;
  const int w = t >> 6, lane = t & 63, quad = lane >> 4, lc = lane & 15;
  const int mw = (w & 1) * 64, nw = (w >> 1) * 64;

  const f32x4 ZERO = {0.f, 0.f, 0.f, 0.f};
  f32x4 acc[4][4];
#pragma unroll
  for (int i = 0; i < 4; ++i)
#pragma unroll
    for (int j = 0; j < 4; ++j) acc[i][j] = ZERO;

  const int sr = t >> 2, sc = (t & 3) * 8;
  const size_t arow0 = (size_t)bm * 128, brow0 = (size_t)bn * 128;

  for (int k0 = 0; k0 < K; k0 += 32) {
#pragma unroll
    for (int p = 0; p < 2; ++p) {
      const int r = sr + 64 * p;
      *(u16x8*)&As[r * LD + sc] = *(const u16x8*)&Ah[(arow0 + r) * K + k0 + sc];
      *(u16x8*)&Bs[r * LD + sc] = *(const u16x8*)&Bh[(brow0 + r) * K + k0 + sc];
      if constexpr (NTERM == 3) {
        *(u16x8*)&As[LOFF + r * LD + sc] = *(const u16x8*)&Al[(arow0 + r) * K + k0 + sc];
        *(u16x8*)&Bs[LOFF + r * LD + sc] = *(const u16x8*)&Bl[(brow0 + r) * K + k0 + sc];
      }
    }
    __syncthreads();

    s16x8 a_h[4], b_h[4], a_l[4], b_l[4];
#pragma unroll
    for (int i = 0; i < 4; ++i) {
      a_h[i] = *(const s16x8*)&As[(mw + 16 * i + lc) * LD + 8 * quad];
      b_h[i] = *(const s16x8*)&Bs[(nw + 16 * i + lc) * LD + 8 * quad];
      if constexpr (NTERM == 3) {
        a_l[i] = *(const s16x8*)&As[LOFF + (mw + 16 * i + lc) * LD + 8 * quad];
        b_l[i] = *(const s16x8*)&Bs[LOFF + (nw + 16 * i + lc) * LD + 8 * quad];
      }
    }
#pragma unroll
    for (int i = 0; i < 4; ++i)
#pragma unroll
      for (int j = 0; j < 4; ++j) {
        acc[i][j] = MFMA(a_h[i], b_h[j], acc[i][j]);
        if constexpr (NTERM == 3) {
          acc[i][j] = MFMA(a_h[i], b_l[j], acc[i][j]);
          acc[i][j] = MFMA(a_l[i], b_h[j], acc[i][j]);
        }
      }
    __syncthreads();
  }

#pragma unroll
  for (int i = 0; i < 4; ++i)
#pragma unroll
    for (int j = 0; j < 4; ++j) {
      const int col = bn * 128 + nw + 16 * j + lc;
#pragma unroll
      for (int r = 0; r < 4; ++r) {
        const int row = bm * 128 + mw + 16 * i + 4 * quad + r;
        const float v = acc[i][j][r];
        if constexpr (OMODE == 0) {
          Cf[(size_t)row * N + col] = v;
        } else if constexpr (OMODE == 1) {
          const u16 hv = f2bf(v);
          Ch[(size_t)row * N + col] = hv;
          Cl[(size_t)row * N + col] = f2bf(v - bf2f(hv));
        } else {
          Ch[(size_t)row * N + col] = f2bf(v);
        }
      }
    }
}

// ---------------------------------------------------------------------------
// Flash attention, causal, scores scaled by *sqrt(D)* (per reference!).
// grid (16 qtiles reversed, 16 heads, 2 batches), 256 threads = 4 waves.
// Q-tile 128 rows; wave w owns rows 32w..32w+31 (2 m-tiles of 16).
// K-tile 128 (hi+lo in LDS), V^T tile in LDS, P via LDS (Ps[kcol][qloc]).
// Split-precision QK^T: 3 MFMA terms. LDS total = 141,312 B -> 1 block/CU.
// ---------------------------------------------------------------------------
__global__ __launch_bounds__(256, 1)
void attn(const u16* __restrict__ Qh, const u16* __restrict__ Ql,
          const u16* __restrict__ Kh, const u16* __restrict__ Kl,
          const u16* __restrict__ Vt, u16* __restrict__ Ctx) {
  constexpr int LDK = 136;   // 128 + 8 pad: 272B rows, 16B aligned, 2-way banks
  constexpr int LDP = 36;    // 72B rows: conflict-free b64 writes
  __shared__ u16 Ksh[128 * LDK];
  __shared__ u16 Ksl[128 * LDK];
  __shared__ u16 Vts[128 * LDK];
  __shared__ u16 Ps[4 * 128 * LDP];

  const int qt = 15 - (int)blockIdx.x;   // heaviest tiles first
  const int h = blockIdx.y, b = blockIdx.z;
  const int t = threadIdx.x;
  const int w = t >> 6, lane = t & 63, quad = lane >> 4, lc = lane & 15;

  // Q fragments live in registers for the whole kernel (A-layout:
  // A[m=lane&15][k=quad*8+j], k-step s covers d = 32s..32s+31).
  s16x8 qfh[2][4], qfl[2][4];
#pragma unroll
  for (int mt = 0; mt < 2; ++mt)
#pragma unroll
    for (int s = 0; s < 4; ++s) {
      const size_t g = ((size_t)(b * 2048 + qt * 128 + 32 * w + 16 * mt + lc)) * 2048
                       + h * 128 + 32 * s + 8 * quad;
      qfh[mt][s] = *(const s16x8*)&Qh[g];
      qfl[mt][s] = *(const s16x8*)&Ql[g];
    }

  const f32x4 ZERO = {0.f, 0.f, 0.f, 0.f};
  float m_run[2][4], l_run[2][4];
  f32x4 o[2][8];
#pragma unroll
  for (int mt = 0; mt < 2; ++mt) {
#pragma unroll
    for (int r = 0; r < 4; ++r) { m_run[mt][r] = -3.0e38f; l_run[mt][r] = 0.f; }
#pragma unroll
    for (int dt = 0; dt < 8; ++dt) o[mt][dt] = ZERO;
  }

  u16* myP = &Ps[w * 128 * LDP];
  const float SC = 11.313708498984760f;  // sqrt(128): reference MULTIPLIES

  const u16* gKh0 = Kh + ((size_t)(b * 2048)) * 2048 + h * 128;
  const u16* gKl0 = Kl + ((size_t)(b * 2048)) * 2048 + h * 128;
  const u16* gV0  = Vt + ((size_t)((b * 16 + h) * 128)) * 2048;

  for (int kt = 0; kt <= qt; ++kt) {
    // ---- stage K hi/lo and V^T tiles (coalesced 16B loads) ----
    {
      const u16* gKhp = gKh0 + (size_t)(kt * 128) * 2048;
      const u16* gKlp = gKl0 + (size_t)(kt * 128) * 2048;
      const u16* gVp  = gV0 + kt * 128;
      const int c = (t & 15) * 8;
#pragma unroll
      for (int p = 0; p < 8; ++p) {
        const int r = (t >> 4) + 16 * p;
        *(u16x8*)&Ksh[r * LDK + c] = *(const u16x8*)&gKhp[(size_t)r * 2048 + c];
        *(u16x8*)&Ksl[r * LDK + c] = *(const u16x8*)&gKlp[(size_t)r * 2048 + c];
        *(u16x8*)&Vts[r * LDK + c] = *(const u16x8*)&gVp[(size_t)r * 2048 + c];
      }
    }
    __syncthreads();

    // ---- S = Q K^T, split precision ----
    f32x4 acc[2][8];
#pragma unroll
    for (int mt = 0; mt < 2; ++mt)
#pragma unroll
      for (int c8 = 0; c8 < 8; ++c8) acc[mt][c8] = ZERO;

#pragma unroll
    for (int c8 = 0; c8 < 8; ++c8) {
#pragma unroll
      for (int s = 0; s < 4; ++s) {
        const s16x8 bh = *(const s16x8*)&Ksh[(16 * c8 + lc) * LDK + 32 * s + 8 * quad];
        const s16x8 bl = *(const s16x8*)&Ksl[(16 * c8 + lc) * LDK + 32 * s + 8 * quad];
#pragma unroll
        for (int mt = 0; mt < 2; ++mt) {
          acc[mt][c8] = MFMA(qfh[mt][s], bh, acc[mt][c8]);
          acc[mt][c8] = MFMA(qfh[mt][s], bl, acc[mt][c8]);
          acc[mt][c8] = MFMA(qfl[mt][s], bh, acc[mt][c8]);
        }
      }
    }

    // ---- online softmax (per-row state in registers) ----
    const bool diag = (kt == qt);
#pragma unroll
    for (int mt = 0; mt < 2; ++mt) {
      float pv[8][4];
#pragma unroll
      for (int c8 = 0; c8 < 8; ++c8)
#pragma unroll
        for (int r = 0; r < 4; ++r) {
          float v = acc[mt][c8][r] * SC;
          if (diag && (16 * c8 + lc) > (32 * w + 16 * mt + 4 * quad + r)) v = -3.0e38f;
          pv[c8][r] = v;
        }
#pragma unroll
      for (int r = 0; r < 4; ++r) {
        float mx = pv[0][r];
#pragma unroll
        for (int c8 = 1; c8 < 8; ++c8) mx = fmaxf(mx, pv[c8][r]);
        mx = fmaxf(mx, __shfl_xor(mx, 1));
        mx = fmaxf(mx, __shfl_xor(mx, 2));
        mx = fmaxf(mx, __shfl_xor(mx, 4));
        mx = fmaxf(mx, __shfl_xor(mx, 8));
        const float mn = fmaxf(m_run[mt][r], mx);
        const float al = __expf(m_run[mt][r] - mn);
        m_run[mt][r] = mn;
        float rs = 0.f;
#pragma unroll
        for (int c8 = 0; c8 < 8; ++c8) {
          const float e = __expf(pv[c8][r] - mn);
          pv[c8][r] = e;
          rs += e;
        }
        rs += __shfl_xor(rs, 1);
        rs += __shfl_xor(rs, 2);
        rs += __shfl_xor(rs, 4);
        rs += __shfl_xor(rs, 8);
        l_run[mt][r] = l_run[mt][r] * al + rs;
#pragma unroll
        for (int dt = 0; dt < 8; ++dt) o[mt][dt][r] *= al;
      }
      // pack P (bf16, unnormalized) -> Ps[kcol][qloc], packed b64 writes
#pragma unroll
      for (int c8 = 0; c8 < 8; ++c8) {
        u16x4 pk;
#pragma unroll
        for (int r = 0; r < 4; ++r) pk[r] = f2bf(pv[c8][r]);
        *(u16x4*)&myP[(16 * c8 + lc) * LDP + 16 * mt + 4 * quad] = pk;
      }
    }

    // ---- O += P * V  (A-frag from Ps, B-frag contiguous from V^T) ----
#pragma unroll
    for (int s = 0; s < 4; ++s) {
      s16x8 af[2];
#pragma unroll
      for (int mt = 0; mt < 2; ++mt) {
        s16x8 a;
#pragma unroll
        for (int j = 0; j < 8; ++j)
          a[j] = (short)myP[(32 * s + 8 * quad + j) * LDP + 16 * mt + lc];
        af[mt] = a;
      }
#pragma unroll
      for (int dt = 0; dt < 8; ++dt) {
        const s16x8 bv = *(const s16x8*)&Vts[(16 * dt + lc) * LDK + 32 * s + 8 * quad];
#pragma unroll
        for (int mt = 0; mt < 2; ++mt) o[mt][dt] = MFMA(af[mt], bv, o[mt][dt]);
      }
    }
    __syncthreads();   // protect K/V tiles before next stage
  }

  // ---- normalize + store bf16 ctx (B,S,H) ----
#pragma unroll
  for (int mt = 0; mt < 2; ++mt)
#pragma unroll
    for (int dt = 0; dt < 8; ++dt)
#pragma unroll
      for (int r = 0; r < 4; ++r) {
        const int row = qt * 128 + 32 * w + 16 * mt + 4 * quad + r;
        const float v = o[mt][dt][r] / l_run[mt][r];
        Ctx[((size_t)(b * 2048 + row)) * 2048 + h * 128 + 16 * dt + lc] = f2bf(v);
      }
}

// ---------------------------------------------------------------------------
extern "C" void kernel_launch(void* const* d_in, const int* in_sizes, int n_in,
                              void* d_out, int out_size, void* d_ws, size_t ws_size,
                              hipStream_t stream) {
  const float* x  = (const float*)d_in[0];
  const float* Wq = (const float*)d_in[1];
  const float* Wk = (const float*)d_in[2];
  const float* Wv = (const float*)d_in[3];
  const float* Wo = (const float*)d_in[4];
  float* out = (float*)d_out;

  char* ws = (char*)d_ws;
  size_t off = 0;
  auto alloc = [&](size_t bytes) {
    char* p = ws + off;
    off += (bytes + 255) & ~(size_t)255;
    return p;
  };
  const size_t XE = (size_t)4096 * 2048;   // B*S x H elements
  const size_t WE = (size_t)2048 * 2048;

  u16* xh  = (u16*)alloc(XE * 2);
  u16* xl  = (u16*)alloc(XE * 2);
  u16* Wqh = (u16*)alloc(WE * 2);
  u16* Wql = (u16*)alloc(WE * 2);
  u16* Wkh = (u16*)alloc(WE * 2);
  u16* Wkl = (u16*)alloc(WE * 2);
  u16* Wvh = (u16*)alloc(WE * 2);
  u16* Woh = (u16*)alloc(WE * 2);
  u16* Qhb = (u16*)alloc(XE * 2);
  u16* Qlb = (u16*)alloc(XE * 2);
  u16* Khb = (u16*)alloc(XE * 2);
  u16* Klb = (u16*)alloc(XE * 2);
  u16* Vb  = (u16*)alloc(XE * 2);
  u16* Vtb = (u16*)alloc(XE * 2);
  u16* Ctxb = (u16*)alloc(XE * 2);
  float* cosT = (float*)alloc((size_t)2048 * 64 * 4);
  float* sinT = (float*)alloc((size_t)2048 * 64 * 4);
  (void)ws_size;  // requires ~203 MB of workspace
  (void)in_sizes; (void)n_in; (void)out_size;

  // 1) precision split + RoPE tables
  split_bf16<<<8192, 256, 0, stream>>>(x, xh, xl, (int)(XE / 4));
  split_bf16<<<4096, 256, 0, stream>>>(Wq, Wqh, Wql, (int)(WE / 4));
  split_bf16<<<4096, 256, 0, stream>>>(Wk, Wkh, Wkl, (int)(WE / 4));
  split_bf16<<<4096, 256, 0, stream>>>(Wv, Wvh, nullptr, (int)(WE / 4));
  split_bf16<<<4096, 256, 0, stream>>>(Wo, Woh, nullptr, (int)(WE / 4));
  rope_tab<<<512, 256, 0, stream>>>(cosT, sinT);

  // 2) projections: Q,K split-precision (3-term), V plain bf16
  gemm_bt<3, 1><<<dim3(16, 32), 256, 0, stream>>>(xh, xl, Wqh, Wql, nullptr, Qhb, Qlb, 4096, 2048, 2048);
  gemm_bt<3, 1><<<dim3(16, 32), 256, 0, stream>>>(xh, xl, Wkh, Wkl, nullptr, Khb, Klb, 4096, 2048, 2048);
  gemm_bt<1, 2><<<dim3(16, 32), 256, 0, stream>>>(xh, nullptr, Wvh, nullptr, nullptr, Vb, nullptr, 4096, 2048, 2048);

  // 3) RoPE in place on Q, K (hi/lo preserved)
  rope_apply<<<16384, 256, 0, stream>>>(Qhb, Qlb, cosT, sinT);
  rope_apply<<<16384, 256, 0, stream>>>(Khb, Klb, cosT, sinT);

  // 4) V -> V^T per head for contiguous PV B-fragments
  transpose_v<<<dim3(256, 16, 2), 256, 0, stream>>>(Vb, Vtb);

  // 5) causal flash attention
  attn<<<dim3(16, 16, 2), 256, 0, stream>>>(Qhb, Qlb, Khb, Klb, Vtb, Ctxb);

  // 6) output projection -> fp32 d_out
  gemm_bt<1, 0><<<dim3(16, 32), 256, 0, stream>>>(Ctxb, nullptr, Woh, nullptr, out, nullptr, nullptr, 4096, 2048, 2048);
}

// Round 2
// 726.349 us; speedup vs baseline: 1.3281x; 1.3281x over previous
//
#include <hip/hip_runtime.h>
#include <cmath>

// ============================================================================
// AutoregressiveGroupQuerySelfAttention  (B=2, S=2048, H=2048, nH=16, D=128)
//
// Round 2: attention occupancy fix.
//  - attn: 512 threads (8 waves x 16 q-rows), 2 waves/SIMD (was 1). LDS 139 KB.
//  - P round-trip: Ps[qrow][kcol] -> PV A-frags are ds_read_b128 (was 64
//    scalar ds_read_u16 per wave per k-tile; 6.7M bank-conflict cycles).
//  - sqrt(D) folded into Q at RoPE time.
//  - Logit path (x, Wq, Wk, QK^T) split precision bf16 hi+lo, 3-term MFMA.
// ============================================================================

typedef unsigned short u16;
typedef __attribute__((ext_vector_type(4))) float  f32x4;
typedef __attribute__((ext_vector_type(4))) float  float4v;
typedef __attribute__((ext_vector_type(4))) unsigned short u16x4;
typedef __attribute__((ext_vector_type(8))) unsigned short u16x8;
typedef __attribute__((ext_vector_type(8))) short s16x8;

__device__ __forceinline__ u16 f2bf(float f) {
  unsigned u = __float_as_uint(f);
  u += 0x7FFFu + ((u >> 16) & 1u);            // RNE; inputs are finite
  return (u16)(u >> 16);
}
__device__ __forceinline__ float bf2f(u16 h) {
  return __uint_as_float(((unsigned)h) << 16);
}
__device__ __forceinline__ f32x4 MFMA(s16x8 a, s16x8 b, f32x4 c) {
  return __builtin_amdgcn_mfma_f32_16x16x32_bf16(a, b, c, 0, 0, 0);
}

// ---------------------------------------------------------------------------
// fp32 -> bf16 hi (+ optional lo residual).  n4 = element count / 4.
// ---------------------------------------------------------------------------
__global__ void split_bf16(const float* __restrict__ src, u16* __restrict__ hi,
                           u16* __restrict__ lo, int n4) {
  int i = blockIdx.x * 256 + threadIdx.x;
  if (i >= n4) return;
  float4v v = ((const float4v*)src)[i];
  u16x4 hv, lv;
#pragma unroll
  for (int j = 0; j < 4; ++j) {
    float f = v[j];
    u16 h = f2bf(f);
    hv[j] = h;
    lv[j] = f2bf(f - bf2f(h));
  }
  ((u16x4*)hi)[i] = hv;
  if (lo) ((u16x4*)lo)[i] = lv;
}

// ---------------------------------------------------------------------------
// RoPE tables in fp64.
// ---------------------------------------------------------------------------
__global__ void rope_tab(float* __restrict__ cosT, float* __restrict__ sinT) {
  int idx = blockIdx.x * 256 + threadIdx.x;   // 2048*64
  int i = idx & 63, s = idx >> 6;
  double invf = pow(10000.0, -(double)i / 64.0);
  double ang = (double)s * invf;
  cosT[idx] = (float)cos(ang);
  sinT[idx] = (float)sin(ang);
}

// ---------------------------------------------------------------------------
// In-place RoPE on a bf16 hi/lo pair array laid out (B*S, H=2048).
// scale: extra multiplier folded into the output (sqrt(D) for Q, 1 for K).
// ---------------------------------------------------------------------------
__global__ void rope_apply(u16* __restrict__ Xh, u16* __restrict__ Xl,
                           const float* __restrict__ cosT,
                           const float* __restrict__ sinT, float scale) {
  int idx = blockIdx.x * 256 + threadIdx.x;   // 2*2048*16*64 = 4,194,304
  int i = idx & 63;
  int hh = (idx >> 6) & 15;
  int row = idx >> 10;                        // b*2048 + s
  int s = row & 2047;
  size_t base = (size_t)row * 2048 + hh * 128;
  size_t c1 = base + i, c2 = c1 + 64;
  float x1 = bf2f(Xh[c1]) + bf2f(Xl[c1]);
  float x2 = bf2f(Xh[c2]) + bf2f(Xl[c2]);
  float cs = cosT[s * 64 + i], sn = sinT[s * 64 + i];
  float o1 = (x1 * cs - x2 * sn) * scale;
  float o2 = (x2 * cs + x1 * sn) * scale;
  u16 h1 = f2bf(o1); Xh[c1] = h1; Xl[c1] = f2bf(o1 - bf2f(h1));
  u16 h2 = f2bf(o2); Xh[c2] = h2; Xl[c2] = f2bf(o2 - bf2f(h2));
}

// ---------------------------------------------------------------------------
// V (B,S,16*128) bf16  ->  Vt (B,16,128,S) bf16   (per-head transpose)
// ---------------------------------------------------------------------------
__global__ void transpose_v(const u16* __restrict__ Vb, u16* __restrict__ Vt) {
  __shared__ u16 tile[32][40];
  int st = blockIdx.x >> 2;
  int dt = blockIdx.x & 3;
  int h = blockIdx.y, b = blockIdx.z;
  int t = threadIdx.x;
  int r = t >> 3, c = (t & 7) * 4;
  const u16* src = Vb + ((size_t)(b * 2048 + st * 32 + r)) * 2048 + h * 128 + dt * 32 + c;
  *(u16x4*)&tile[r][c] = *(const u16x4*)src;
  __syncthreads();
  u16x4 o;
#pragma unroll
  for (int j = 0; j < 4; ++j) o[j] = tile[c + j][r];
  u16* dst = Vt + ((size_t)((b * 16 + h) * 128 + dt * 32 + r)) * 2048 + st * 32 + c;
  *(u16x4*)dst = o;
}

// ---------------------------------------------------------------------------
// GEMM  C(MxN) = A(MxK) * B(NxK)^T, bf16 inputs, fp32 accumulate.
// NTERM==3: split precision (hh+hl+lh).  OMODE: 0 fp32, 1 bf16 hi/lo, 2 bf16.
// ---------------------------------------------------------------------------
template <int NTERM, int OMODE>
__global__ __launch_bounds__(256)
void gemm_bt(const u16* __restrict__ Ah, const u16* __restrict__ Al,
             const u16* __restrict__ Bh, const u16* __restrict__ Bl,
             float* __restrict__ Cf, u16* __restrict__ Ch, u16* __restrict__ Cl,
             int M, int N, int K) {
  constexpr int LD = 40;
  constexpr int LOFF = 128 * LD;
  __shared__ u16 As[(NTERM == 3 ? 2 : 1) * 128 * LD];
  __shared__ u16 Bs[(NTERM == 3 ? 2 : 1) * 128 * LD];
  const int bn = blockIdx.x, bm = blockIdx.y;
  const int t = threadIdx.x;
  const int w = t >> 6, lane = t & 63, quad = lane >> 4, lc = lane & 15;
  const int mw = (w & 1) * 64, nw = (w >> 1) * 64;

  const f32x4 ZERO = {0.f, 0.f, 0.f, 0.f};
  f32x4 acc[4][4];
#pragma unroll
  for (int i = 0; i < 4; ++i)
#pragma unroll
    for (int j = 0; j < 4; ++j) acc[i][j] = ZERO;

  const int sr = t >> 2, sc = (t & 3) * 8;
  const size_t arow0 = (size_t)bm * 128, brow0 = (size_t)bn * 128;

  for (int k0 = 0; k0 < K; k0 += 32) {
#pragma unroll
    for (int p = 0; p < 2; ++p) {
      const int r = sr + 64 * p;
      *(u16x8*)&As[r * LD + sc] = *(const u16x8*)&Ah[(arow0 + r) * K + k0 + sc];
      *(u16x8*)&Bs[r * LD + sc] = *(const u16x8*)&Bh[(brow0 + r) * K + k0 + sc];
      if constexpr (NTERM == 3) {
        *(u16x8*)&As[LOFF + r * LD + sc] = *(const u16x8*)&Al[(arow0 + r) * K + k0 + sc];
        *(u16x8*)&Bs[LOFF + r * LD + sc] = *(const u16x8*)&Bl[(brow0 + r) * K + k0 + sc];
      }
    }
    __syncthreads();

    s16x8 a_h[4], b_h[4], a_l[4], b_l[4];
#pragma unroll
    for (int i = 0; i < 4; ++i) {
      a_h[i] = *(const s16x8*)&As[(mw + 16 * i + lc) * LD + 8 * quad];
      b_h[i] = *(const s16x8*)&Bs[(nw + 16 * i + lc) * LD + 8 * quad];
      if constexpr (NTERM == 3) {
        a_l[i] = *(const s16x8*)&As[LOFF + (mw + 16 * i + lc) * LD + 8 * quad];
        b_l[i] = *(const s16x8*)&Bs[LOFF + (nw + 16 * i + lc) * LD + 8 * quad];
      }
    }
#pragma unroll
    for (int i = 0; i < 4; ++i)
#pragma unroll
      for (int j = 0; j < 4; ++j) {
        acc[i][j] = MFMA(a_h[i], b_h[j], acc[i][j]);
        if constexpr (NTERM == 3) {
          acc[i][j] = MFMA(a_h[i], b_l[j], acc[i][j]);
          acc[i][j] = MFMA(a_l[i], b_h[j], acc[i][j]);
        }
      }
    __syncthreads();
  }

#pragma unroll
  for (int i = 0; i < 4; ++i)
#pragma unroll
    for (int j = 0; j < 4; ++j) {
      const int col = bn * 128 + nw + 16 * j + lc;
#pragma unroll
      for (int r = 0; r < 4; ++r) {
        const int row = bm * 128 + mw + 16 * i + 4 * quad + r;
        const float v = acc[i][j][r];
        if constexpr (OMODE == 0) {
          Cf[(size_t)row * N + col] = v;
        } else if constexpr (OMODE == 1) {
          const u16 hv = f2bf(v);
          Ch[(size_t)row * N + col] = hv;
          Cl[(size_t)row * N + col] = f2bf(v - bf2f(hv));
        } else {
          Ch[(size_t)row * N + col] = f2bf(v);
        }
      }
    }
}

// ---------------------------------------------------------------------------
// Flash attention, causal. Q pre-scaled by sqrt(D) (folded into RoPE).
// grid (16 qtiles reversed, 16 heads, 2 batches), 512 threads = 8 waves.
// Wave w owns q-rows 16w..16w+15 (one 16-row m-tile). K-tile 128 (hi+lo).
// Ps[qrow][kcol]: scalar b16 writes (2-way banks, free), b128 A-frag reads.
// LDS = 139,264 B -> 1 block/CU, 8 waves = 2 waves/SIMD.
// ---------------------------------------------------------------------------
__global__ __launch_bounds__(512, 2)
void attn(const u16* __restrict__ Qh, const u16* __restrict__ Ql,
          const u16* __restrict__ Kh, const u16* __restrict__ Kl,
          const u16* __restrict__ Vt, u16* __restrict__ Ctx) {
  constexpr int LDK = 136;   // 128 + 8 pad: 272B rows, 16B aligned
  constexpr int LDP = 136;
  __shared__ u16 Ksh[128 * LDK];
  __shared__ u16 Ksl[128 * LDK];
  __shared__ u16 Vts[128 * LDK];
  __shared__ u16 Ps[128 * LDP];

  const int qt = 15 - (int)blockIdx.x;   // heaviest tiles first
  const int h = blockIdx.y, b = blockIdx.z;
  const int t = threadIdx.x;
  const int w = t >> 6, lane = t & 63, quad = lane >> 4, lc = lane & 15;

  // Q fragments in registers for the whole kernel.
  // A-layout: A[m=lane&15][k=quad*8+j]; k-step s covers d = 32s..32s+31.
  s16x8 qfh[4], qfl[4];
#pragma unroll
  for (int s = 0; s < 4; ++s) {
    const size_t g = ((size_t)(b * 2048 + qt * 128 + 16 * w + lc)) * 2048
                     + h * 128 + 32 * s + 8 * quad;
    qfh[s] = *(const s16x8*)&Qh[g];
    qfl[s] = *(const s16x8*)&Ql[g];
  }

  const f32x4 ZERO = {0.f, 0.f, 0.f, 0.f};
  float m_run[4], l_run[4];          // per C-layout row r (qrow = 16w+4quad+r)
  f32x4 o[8];
#pragma unroll
  for (int r = 0; r < 4; ++r) { m_run[r] = -3.0e38f; l_run[r] = 0.f; }
#pragma unroll
  for (int dt = 0; dt < 8; ++dt) o[dt] = ZERO;

  const u16* gKh0 = Kh + ((size_t)(b * 2048)) * 2048 + h * 128;
  const u16* gKl0 = Kl + ((size_t)(b * 2048)) * 2048 + h * 128;
  const u16* gV0  = Vt + ((size_t)((b * 16 + h) * 128)) * 2048;

  for (int kt = 0; kt <= qt; ++kt) {
    // ---- stage K hi/lo and V^T tiles (512 threads, coalesced 16B loads) ----
    {
      const u16* gKhp = gKh0 + (size_t)(kt * 128) * 2048;
      const u16* gKlp = gKl0 + (size_t)(kt * 128) * 2048;
      const u16* gVp  = gV0 + kt * 128;
      const int c = (t & 15) * 8;
#pragma unroll
      for (int p = 0; p < 4; ++p) {
        const int r = (t >> 4) + 32 * p;
        *(u16x8*)&Ksh[r * LDK + c] = *(const u16x8*)&gKhp[(size_t)r * 2048 + c];
        *(u16x8*)&Ksl[r * LDK + c] = *(const u16x8*)&gKlp[(size_t)r * 2048 + c];
        *(u16x8*)&Vts[r * LDK + c] = *(const u16x8*)&gVp[(size_t)r * 2048 + c];
      }
    }
    __syncthreads();

    // ---- S = Q K^T, split precision (Q already carries sqrt(D)) ----
    f32x4 acc[8];
#pragma unroll
    for (int c8 = 0; c8 < 8; ++c8) acc[c8] = ZERO;
#pragma unroll
    for (int c8 = 0; c8 < 8; ++c8) {
#pragma unroll
      for (int s = 0; s < 4; ++s) {
        const s16x8 bh = *(const s16x8*)&Ksh[(16 * c8 + lc) * LDK + 32 * s + 8 * quad];
        const s16x8 bl = *(const s16x8*)&Ksl[(16 * c8 + lc) * LDK + 32 * s + 8 * quad];
        acc[c8] = MFMA(qfh[s], bh, acc[c8]);
        acc[c8] = MFMA(qfh[s], bl, acc[c8]);
        acc[c8] = MFMA(qfl[s], bh, acc[c8]);
      }
    }

    // ---- online softmax (state per C-layout row, replicated across lc) ----
    const bool diag = (kt == qt);
    float pv[8][4];
#pragma unroll
    for (int c8 = 0; c8 < 8; ++c8)
#pragma unroll
      for (int r = 0; r < 4; ++r) {
        float v = acc[c8][r];
        if (diag && (16 * c8 + lc) > (16 * w + 4 * quad + r)) v = -3.0e38f;
        pv[c8][r] = v;
      }
#pragma unroll
    for (int r = 0; r < 4; ++r) {
      float mx = pv[0][r];
#pragma unroll
      for (int c8 = 1; c8 < 8; ++c8) mx = fmaxf(mx, pv[c8][r]);
      mx = fmaxf(mx, __shfl_xor(mx, 1));
      mx = fmaxf(mx, __shfl_xor(mx, 2));
      mx = fmaxf(mx, __shfl_xor(mx, 4));
      mx = fmaxf(mx, __shfl_xor(mx, 8));
      const float mn = fmaxf(m_run[r], mx);
      const float al = __expf(m_run[r] - mn);
      m_run[r] = mn;
      float rs = 0.f;
#pragma unroll
      for (int c8 = 0; c8 < 8; ++c8) {
        const float e = __expf(pv[c8][r] - mn);
        pv[c8][r] = e;
        rs += e;
      }
      rs += __shfl_xor(rs, 1);
      rs += __shfl_xor(rs, 2);
      rs += __shfl_xor(rs, 4);
      rs += __shfl_xor(rs, 8);
      l_run[r] = l_run[r] * al + rs;
#pragma unroll
      for (int dt = 0; dt < 8; ++dt) o[dt][r] *= al;
    }
    // pack P (bf16, unnormalized) -> Ps[qrow][kcol] (scalar b16 writes)
#pragma unroll
    for (int c8 = 0; c8 < 8; ++c8)
#pragma unroll
      for (int r = 0; r < 4; ++r)
        Ps[(16 * w + 4 * quad + r) * LDP + 16 * c8 + lc] = f2bf(pv[c8][r]);

    // ---- O += P * V  (A-frag: b128 from own rows; B-frag from V^T) ----
#pragma unroll
    for (int s = 0; s < 4; ++s) {
      const s16x8 af = *(const s16x8*)&Ps[(16 * w + lc) * LDP + 32 * s + 8 * quad];
#pragma unroll
      for (int dt = 0; dt < 8; ++dt) {
        const s16x8 bv = *(const s16x8*)&Vts[(16 * dt + lc) * LDK + 32 * s + 8 * quad];
        o[dt] = MFMA(af, bv, o[dt]);
      }
    }
    __syncthreads();   // protect K/V tiles before next stage
  }

  // ---- normalize + store bf16 ctx (B,S,H) ----
#pragma unroll
  for (int dt = 0; dt < 8; ++dt)
#pragma unroll
    for (int r = 0; r < 4; ++r) {
      const int row = qt * 128 + 16 * w + 4 * quad + r;
      const float v = o[dt][r] / l_run[r];
      Ctx[((size_t)(b * 2048 + row)) * 2048 + h * 128 + 16 * dt + lc] = f2bf(v);
    }
}

// ---------------------------------------------------------------------------
extern "C" void kernel_launch(void* const* d_in, const int* in_sizes, int n_in,
                              void* d_out, int out_size, void* d_ws, size_t ws_size,
                              hipStream_t stream) {
  const float* x  = (const float*)d_in[0];
  const float* Wq = (const float*)d_in[1];
  const float* Wk = (const float*)d_in[2];
  const float* Wv = (const float*)d_in[3];
  const float* Wo = (const float*)d_in[4];
  float* out = (float*)d_out;

  char* ws = (char*)d_ws;
  size_t off = 0;
  auto alloc = [&](size_t bytes) {
    char* p = ws + off;
    off += (bytes + 255) & ~(size_t)255;
    return p;
  };
  const size_t XE = (size_t)4096 * 2048;   // B*S x H elements
  const size_t WE = (size_t)2048 * 2048;

  u16* xh  = (u16*)alloc(XE * 2);
  u16* xl  = (u16*)alloc(XE * 2);
  u16* Wqh = (u16*)alloc(WE * 2);
  u16* Wql = (u16*)alloc(WE * 2);
  u16* Wkh = (u16*)alloc(WE * 2);
  u16* Wkl = (u16*)alloc(WE * 2);
  u16* Wvh = (u16*)alloc(WE * 2);
  u16* Woh = (u16*)alloc(WE * 2);
  u16* Qhb = (u16*)alloc(XE * 2);
  u16* Qlb = (u16*)alloc(XE * 2);
  u16* Khb = (u16*)alloc(XE * 2);
  u16* Klb = (u16*)alloc(XE * 2);
  u16* Vb  = (u16*)alloc(XE * 2);
  u16* Vtb = (u16*)alloc(XE * 2);
  u16* Ctxb = (u16*)alloc(XE * 2);
  float* cosT = (float*)alloc((size_t)2048 * 64 * 4);
  float* sinT = (float*)alloc((size_t)2048 * 64 * 4);
  (void)ws_size;  // requires ~203 MB of workspace
  (void)in_sizes; (void)n_in; (void)out_size;

  // 1) precision split + RoPE tables
  split_bf16<<<8192, 256, 0, stream>>>(x, xh, xl, (int)(XE / 4));
  split_bf16<<<4096, 256, 0, stream>>>(Wq, Wqh, Wql, (int)(WE / 4));
  split_bf16<<<4096, 256, 0, stream>>>(Wk, Wkh, Wkl, (int)(WE / 4));
  split_bf16<<<4096, 256, 0, stream>>>(Wv, Wvh, nullptr, (int)(WE / 4));
  split_bf16<<<4096, 256, 0, stream>>>(Wo, Woh, nullptr, (int)(WE / 4));
  rope_tab<<<512, 256, 0, stream>>>(cosT, sinT);

  // 2) projections: Q,K split-precision (3-term), V plain bf16
  gemm_bt<3, 1><<<dim3(16, 32), 256, 0, stream>>>(xh, xl, Wqh, Wql, nullptr, Qhb, Qlb, 4096, 2048, 2048);
  gemm_bt<3, 1><<<dim3(16, 32), 256, 0, stream>>>(xh, xl, Wkh, Wkl, nullptr, Khb, Klb, 4096, 2048, 2048);
  gemm_bt<1, 2><<<dim3(16, 32), 256, 0, stream>>>(xh, nullptr, Wvh, nullptr, nullptr, Vb, nullptr, 4096, 2048, 2048);

  // 3) RoPE in place on Q (x sqrt(D)) and K
  rope_apply<<<16384, 256, 0, stream>>>(Qhb, Qlb, cosT, sinT, 11.313708498984760f);
  rope_apply<<<16384, 256, 0, stream>>>(Khb, Klb, cosT, sinT, 1.0f);

  // 4) V -> V^T per head for contiguous PV B-fragments
  transpose_v<<<dim3(256, 16, 2), 256, 0, stream>>>(Vb, Vtb);

  // 5) causal flash attention
  attn<<<dim3(16, 16, 2), 512, 0, stream>>>(Qhb, Qlb, Khb, Klb, Vtb, Ctxb);

  // 6) output projection -> fp32 d_out
  gemm_bt<1, 0><<<dim3(16, 32), 256, 0, stream>>>(Ctxb, nullptr, Woh, nullptr, out, nullptr, nullptr, 4096, 2048, 2048);
}

// Round 3
// 697.277 us; speedup vs baseline: 1.3835x; 1.0417x over previous
//
#include <hip/hip_runtime.h>
#include <cmath>

// ============================================================================
// AutoregressiveGroupQuerySelfAttention  (B=2, S=2048, H=2048, nH=16, D=128)
//
// Round 3:
//  - GEMM: global_load_lds width=16 staging (m97 pattern), unpadded LDS,
//    wave tile 32x128 so RoPE pairs (d, d+64) sit in-lane -> RoPE fused into
//    Q/K GEMM epilogues (fp32 rotation; rope_apply kernels deleted).
//  - attn: kN=64 K-tiles, double-buffered LDS (125 KB), VGPR prefetch of
//    tile kt+1 during compute on kt, single barrier per iteration.
//  - Logit path (x, Wq, Wk, QK^T) split precision bf16 hi+lo, 3-term MFMA.
// ============================================================================

typedef unsigned short u16;
typedef __attribute__((ext_vector_type(4))) float  f32x4;
typedef __attribute__((ext_vector_type(4))) float  float4v;
typedef __attribute__((ext_vector_type(4))) unsigned short u16x4;
typedef __attribute__((ext_vector_type(8))) unsigned short u16x8;
typedef __attribute__((ext_vector_type(8))) short s16x8;

__device__ __forceinline__ u16 f2bf(float f) {
  unsigned u = __float_as_uint(f);
  u += 0x7FFFu + ((u >> 16) & 1u);            // RNE; inputs are finite
  return (u16)(u >> 16);
}
__device__ __forceinline__ float bf2f(u16 h) {
  return __uint_as_float(((unsigned)h) << 16);
}
__device__ __forceinline__ f32x4 MFMA(s16x8 a, s16x8 b, f32x4 c) {
  return __builtin_amdgcn_mfma_f32_16x16x32_bf16(a, b, c, 0, 0, 0);
}
// async global->LDS, 16B per lane; LDS dest = wave-uniform base + lane*16
__device__ __forceinline__ void gld16(const void* g, void* s) {
  __builtin_amdgcn_global_load_lds(
      (const __attribute__((address_space(1))) void*)g,
      (__attribute__((address_space(3))) void*)s, 16, 0, 0);
}

// ---------------------------------------------------------------------------
// fp32 -> bf16 hi (+ optional lo residual).  n4 = element count / 4.
// ---------------------------------------------------------------------------
__global__ void split_bf16(const float* __restrict__ src, u16* __restrict__ hi,
                           u16* __restrict__ lo, int n4) {
  int i = blockIdx.x * 256 + threadIdx.x;
  if (i >= n4) return;
  float4v v = ((const float4v*)src)[i];
  u16x4 hv, lv;
#pragma unroll
  for (int j = 0; j < 4; ++j) {
    float f = v[j];
    u16 h = f2bf(f);
    hv[j] = h;
    lv[j] = f2bf(f - bf2f(h));
  }
  ((u16x4*)hi)[i] = hv;
  if (lo) ((u16x4*)lo)[i] = lv;
}

// ---------------------------------------------------------------------------
// RoPE tables in fp64.
// ---------------------------------------------------------------------------
__global__ void rope_tab(float* __restrict__ cosT, float* __restrict__ sinT) {
  int idx = blockIdx.x * 256 + threadIdx.x;   // 2048*64
  int i = idx & 63, s = idx >> 6;
  double invf = pow(10000.0, -(double)i / 64.0);
  double ang = (double)s * invf;
  cosT[idx] = (float)cos(ang);
  sinT[idx] = (float)sin(ang);
}

// ---------------------------------------------------------------------------
// V (B,S,16*128) bf16  ->  Vt (B,16,128,S) bf16   (per-head transpose)
// ---------------------------------------------------------------------------
__global__ void transpose_v(const u16* __restrict__ Vb, u16* __restrict__ Vt) {
  __shared__ u16 tile[32][40];
  int st = blockIdx.x >> 2;
  int dt = blockIdx.x & 3;
  int h = blockIdx.y, b = blockIdx.z;
  int t = threadIdx.x;
  int r = t >> 3, c = (t & 7) * 4;
  const u16* src = Vb + ((size_t)(b * 2048 + st * 32 + r)) * 2048 + h * 128 + dt * 32 + c;
  *(u16x4*)&tile[r][c] = *(const u16x4*)src;
  __syncthreads();
  u16x4 o;
#pragma unroll
  for (int j = 0; j < 4; ++j) o[j] = tile[c + j][r];
  u16* dst = Vt + ((size_t)((b * 16 + h) * 128 + dt * 32 + r)) * 2048 + st * 32 + c;
  *(u16x4*)dst = o;
}

// ---------------------------------------------------------------------------
// GEMM  C(MxN) = A(MxK) * B(NxK)^T, bf16 inputs, fp32 accumulate.
// NTERM==3: split precision (hh+hl+lh).
// OMODE: 0 fp32, 1 bf16 hi/lo, 2 bf16.   ROPE: fuse rotation in epilogue.
// 128x128 tile, BK=32, 4 waves each 32(m) x 128(n): acc[2][8].
// Staging via global_load_lds (16B/lane), unpadded LDS [128][32].
// ---------------------------------------------------------------------------
template <int NTERM, int OMODE, int ROPE>
__global__ __launch_bounds__(256, 3)
void gemm_bt(const u16* __restrict__ Ah, const u16* __restrict__ Al,
             const u16* __restrict__ Bh, const u16* __restrict__ Bl,
             float* __restrict__ Cf, u16* __restrict__ Ch, u16* __restrict__ Cl,
             const float* __restrict__ cosT, const float* __restrict__ sinT,
             float scale, int M, int N, int K) {
  __shared__ u16 As[128 * 32];
  __shared__ u16 Bs[128 * 32];
  __shared__ u16 Asl[NTERM == 3 ? 128 * 32 : 8];
  __shared__ u16 Bsl[NTERM == 3 ? 128 * 32 : 8];
  const int bn = blockIdx.x, bm = blockIdx.y;
  const int t = threadIdx.x;
  const int w = t >> 6, lane = t & 63, quad = lane >> 4, lc = lane & 15;

  const f32x4 ZERO = {0.f, 0.f, 0.f, 0.f};
  f32x4 acc[2][8];
#pragma unroll
  for (int i = 0; i < 2; ++i)
#pragma unroll
    for (int j = 0; j < 8; ++j) acc[i][j] = ZERO;

  // staging map: chunk (w,p) -> LDS bytes [(2w+p)*1024, +1024); lane covers 16B.
  // element row = (2w+p)*16 + (lane>>2), col = (lane&3)*8
  const int sr0 = (lane >> 2);
  const int sc0 = (lane & 3) * 8;
  const size_t arow0 = (size_t)bm * 128, brow0 = (size_t)bn * 128;

  for (int k0 = 0; k0 < K; k0 += 32) {
#pragma unroll
    for (int p = 0; p < 2; ++p) {
      const int ch = 2 * w + p;
      const int r = ch * 16 + sr0;
      const size_t ga = (arow0 + r) * (size_t)K + k0 + sc0;
      const size_t gb = (brow0 + r) * (size_t)K + k0 + sc0;
      const int ldso = ch * 512 + lane * 8;   // u16 index
      gld16(&Ah[ga], &As[ldso]);
      gld16(&Bh[gb], &Bs[ldso]);
      if constexpr (NTERM == 3) {
        gld16(&Al[ga], &Asl[ldso]);
        gld16(&Bl[gb], &Bsl[ldso]);
      }
    }
    __syncthreads();

    s16x8 ah[2], al[2];
#pragma unroll
    for (int i = 0; i < 2; ++i) {
      ah[i] = *(const s16x8*)&As[(32 * w + 16 * i + lc) * 32 + 8 * quad];
      if constexpr (NTERM == 3)
        al[i] = *(const s16x8*)&Asl[(32 * w + 16 * i + lc) * 32 + 8 * quad];
    }
#pragma unroll
    for (int j = 0; j < 8; ++j) {
      const s16x8 bh = *(const s16x8*)&Bs[(16 * j + lc) * 32 + 8 * quad];
      s16x8 bl;
      if constexpr (NTERM == 3)
        bl = *(const s16x8*)&Bsl[(16 * j + lc) * 32 + 8 * quad];
#pragma unroll
      for (int i = 0; i < 2; ++i) {
        acc[i][j] = MFMA(ah[i], bh, acc[i][j]);
        if constexpr (NTERM == 3) {
          acc[i][j] = MFMA(ah[i], bl, acc[i][j]);
          acc[i][j] = MFMA(al[i], bh, acc[i][j]);
        }
      }
    }
    __syncthreads();
  }

  // ---- epilogue ----
  if constexpr (ROPE) {
    // N-tile 128 == one head (bn*128 head-aligned). Pair cols d and d+64.
#pragma unroll
    for (int i = 0; i < 2; ++i)
#pragma unroll
      for (int r = 0; r < 4; ++r) {
        const int row = bm * 128 + 32 * w + 16 * i + 4 * quad + r;
        const int s = row & 2047;
#pragma unroll
        for (int j = 0; j < 4; ++j) {
          const int hd = 16 * j + lc;
          const float cs = cosT[s * 64 + hd], sn = sinT[s * 64 + hd];
          const float q1 = acc[i][j][r], q2 = acc[i][j + 4][r];
          const float o1 = (q1 * cs - q2 * sn) * scale;
          const float o2 = (q2 * cs + q1 * sn) * scale;
          const size_t p1 = (size_t)row * N + bn * 128 + hd;
          const u16 h1 = f2bf(o1);
          Ch[p1] = h1; Cl[p1] = f2bf(o1 - bf2f(h1));
          const u16 h2 = f2bf(o2);
          Ch[p1 + 64] = h2; Cl[p1 + 64] = f2bf(o2 - bf2f(h2));
        }
      }
  } else {
#pragma unroll
    for (int i = 0; i < 2; ++i)
#pragma unroll
      for (int j = 0; j < 8; ++j) {
        const int col = bn * 128 + 16 * j + lc;
#pragma unroll
        for (int r = 0; r < 4; ++r) {
          const int row = bm * 128 + 32 * w + 16 * i + 4 * quad + r;
          const float v = acc[i][j][r];
          if constexpr (OMODE == 0) {
            Cf[(size_t)row * N + col] = v;
          } else if constexpr (OMODE == 1) {
            const u16 hv = f2bf(v);
            Ch[(size_t)row * N + col] = hv;
            Cl[(size_t)row * N + col] = f2bf(v - bf2f(hv));
          } else {
            Ch[(size_t)row * N + col] = f2bf(v);
          }
        }
      }
  }
}

// ---------------------------------------------------------------------------
// Flash attention, causal. Q pre-scaled by sqrt(D) (folded into GEMM epilogue).
// grid (16 qtiles reversed, 16 heads, 2 batches), 512 threads = 8 waves.
// Wave w owns q-rows 16w..16w+15. K-step 64, double-buffered LDS:
//   Ksh/Ksl[2][64x136], Vts[2][128x72], Ps[128x72]  -> 125 KB, 1 block/CU.
// Per iter: prefetch kt+1 global->VGPR, compute kt, write VGPR->LDS, barrier.
// ---------------------------------------------------------------------------
__global__ __launch_bounds__(512, 2)
void attn(const u16* __restrict__ Qh, const u16* __restrict__ Ql,
          const u16* __restrict__ Kh, const u16* __restrict__ Kl,
          const u16* __restrict__ Vt, u16* __restrict__ Ctx) {
  constexpr int LDK = 136;   // 64 k-rows x 128 d (+8 pad)
  constexpr int LDV = 72;    // 128 d-rows x 64 s (+8 pad)
  constexpr int LDP = 72;    // 128 q-rows x 64 k (+8 pad)
  __shared__ u16 Ksh[2][64 * LDK];
  __shared__ u16 Ksl[2][64 * LDK];
  __shared__ u16 Vts[2][128 * LDV];
  __shared__ u16 Ps[128 * LDP];

  const int qt = 15 - (int)blockIdx.x;   // heaviest tiles first
  const int h = blockIdx.y, b = blockIdx.z;
  const int t = threadIdx.x;
  const int w = t >> 6, lane = t & 63, quad = lane >> 4, lc = lane & 15;

  // Q fragments in registers (A-layout: A[m=lane&15][k=quad*8+j]).
  s16x8 qfh[4], qfl[4];
#pragma unroll
  for (int s = 0; s < 4; ++s) {
    const size_t g = ((size_t)(b * 2048 + qt * 128 + 16 * w + lc)) * 2048
                     + h * 128 + 32 * s + 8 * quad;
    qfh[s] = *(const s16x8*)&Qh[g];
    qfl[s] = *(const s16x8*)&Ql[g];
  }

  const f32x4 ZERO = {0.f, 0.f, 0.f, 0.f};
  float m_run[4], l_run[4];
  f32x4 o[8];
#pragma unroll
  for (int r = 0; r < 4; ++r) { m_run[r] = -3.0e38f; l_run[r] = 0.f; }
#pragma unroll
  for (int dt = 0; dt < 8; ++dt) o[dt] = ZERO;

  const u16* gKh0 = Kh + ((size_t)(b * 2048)) * 2048 + h * 128;
  const u16* gKl0 = Kl + ((size_t)(b * 2048)) * 2048 + h * 128;
  const u16* gV0  = Vt + ((size_t)((b * 16 + h) * 128)) * 2048;

  const int ktmax = 2 * qt + 1;
  // staging maps
  const int krow = t >> 3;          // 0..63   (K tile row = k index)
  const int kcol = (t & 7) * 8;     // + 64p   (d)
  const int vrow = t >> 2;          // 0..127  (V^T row = d)
  const int vcol = (t & 3) * 8;     // + 32p   (s_local)

  u16x8 pKh[2], pKl[2], pV[2];

  // ---- stage tile 0 ----
#pragma unroll
  for (int p = 0; p < 2; ++p) {
    pKh[p] = *(const u16x8*)&gKh0[(size_t)(0 * 64 + krow) * 2048 + kcol + 64 * p];
    pKl[p] = *(const u16x8*)&gKl0[(size_t)(0 * 64 + krow) * 2048 + kcol + 64 * p];
    pV[p]  = *(const u16x8*)&gV0[(size_t)vrow * 2048 + 0 * 64 + vcol + 32 * p];
  }
#pragma unroll
  for (int p = 0; p < 2; ++p) {
    *(u16x8*)&Ksh[0][krow * LDK + kcol + 64 * p] = pKh[p];
    *(u16x8*)&Ksl[0][krow * LDK + kcol + 64 * p] = pKl[p];
    *(u16x8*)&Vts[0][vrow * LDV + vcol + 32 * p] = pV[p];
  }
  __syncthreads();

  for (int kt = 0; kt <= ktmax; ++kt) {
    const int cur = kt & 1;
    const bool havenext = (kt < ktmax);
    if (havenext) {
#pragma unroll
      for (int p = 0; p < 2; ++p) {
        pKh[p] = *(const u16x8*)&gKh0[(size_t)((kt + 1) * 64 + krow) * 2048 + kcol + 64 * p];
        pKl[p] = *(const u16x8*)&gKl0[(size_t)((kt + 1) * 64 + krow) * 2048 + kcol + 64 * p];
        pV[p]  = *(const u16x8*)&gV0[(size_t)vrow * 2048 + (kt + 1) * 64 + vcol + 32 * p];
      }
    }

    // wave fully above the causal frontier at this k-tile? (only kt=2qt+1)
    const bool active = (qt * 128 + 16 * w + 15) >= kt * 64;
    if (active) {
      // ---- S = Q K^T, split precision ----
      f32x4 acc[4];
#pragma unroll
      for (int c8 = 0; c8 < 4; ++c8) acc[c8] = ZERO;
#pragma unroll
      for (int c8 = 0; c8 < 4; ++c8) {
#pragma unroll
        for (int s = 0; s < 4; ++s) {
          const s16x8 bh = *(const s16x8*)&Ksh[cur][(16 * c8 + lc) * LDK + 32 * s + 8 * quad];
          const s16x8 bl = *(const s16x8*)&Ksl[cur][(16 * c8 + lc) * LDK + 32 * s + 8 * quad];
          acc[c8] = MFMA(qfh[s], bh, acc[c8]);
          acc[c8] = MFMA(qfh[s], bl, acc[c8]);
          acc[c8] = MFMA(qfl[s], bh, acc[c8]);
        }
      }

      // ---- online softmax ----
      const bool diag = (kt >= 2 * qt);
      float pvv[4][4];
#pragma unroll
      for (int c8 = 0; c8 < 4; ++c8)
#pragma unroll
        for (int r = 0; r < 4; ++r) {
          float v = acc[c8][r];
          if (diag && (kt * 64 + 16 * c8 + lc) > (qt * 128 + 16 * w + 4 * quad + r))
            v = -3.0e38f;
          pvv[c8][r] = v;
        }
#pragma unroll
      for (int r = 0; r < 4; ++r) {
        float mx = fmaxf(fmaxf(pvv[0][r], pvv[1][r]), fmaxf(pvv[2][r], pvv[3][r]));
        mx = fmaxf(mx, __shfl_xor(mx, 1));
        mx = fmaxf(mx, __shfl_xor(mx, 2));
        mx = fmaxf(mx, __shfl_xor(mx, 4));
        mx = fmaxf(mx, __shfl_xor(mx, 8));
        const float mn = fmaxf(m_run[r], mx);
        const float al = __expf(m_run[r] - mn);
        m_run[r] = mn;
        float rs = 0.f;
#pragma unroll
        for (int c8 = 0; c8 < 4; ++c8) {
          const float e = __expf(pvv[c8][r] - mn);
          pvv[c8][r] = e;
          rs += e;
        }
        rs += __shfl_xor(rs, 1);
        rs += __shfl_xor(rs, 2);
        rs += __shfl_xor(rs, 4);
        rs += __shfl_xor(rs, 8);
        l_run[r] = l_run[r] * al + rs;
#pragma unroll
        for (int dt = 0; dt < 8; ++dt) o[dt][r] *= al;
      }
      // pack P (bf16, unnormalized) -> Ps[qrow][kcol]; own rows only
#pragma unroll
      for (int c8 = 0; c8 < 4; ++c8)
#pragma unroll
        for (int r = 0; r < 4; ++r)
          Ps[(16 * w + 4 * quad + r) * LDP + 16 * c8 + lc] = f2bf(pvv[c8][r]);

      // ---- O += P * V ----
#pragma unroll
      for (int s = 0; s < 2; ++s) {
        const s16x8 af = *(const s16x8*)&Ps[(16 * w + lc) * LDP + 32 * s + 8 * quad];
#pragma unroll
        for (int dt = 0; dt < 8; ++dt) {
          const s16x8 bv = *(const s16x8*)&Vts[cur][(16 * dt + lc) * LDV + 32 * s + 8 * quad];
          o[dt] = MFMA(af, bv, o[dt]);
        }
      }
    }

    if (havenext) {
      const int nxt = cur ^ 1;
#pragma unroll
      for (int p = 0; p < 2; ++p) {
        *(u16x8*)&Ksh[nxt][krow * LDK + kcol + 64 * p] = pKh[p];
        *(u16x8*)&Ksl[nxt][krow * LDK + kcol + 64 * p] = pKl[p];
        *(u16x8*)&Vts[nxt][vrow * LDV + vcol + 32 * p] = pV[p];
      }
    }
    __syncthreads();
  }

  // ---- normalize + store bf16 ctx (B,S,H) ----
#pragma unroll
  for (int dt = 0; dt < 8; ++dt)
#pragma unroll
    for (int r = 0; r < 4; ++r) {
      const int row = qt * 128 + 16 * w + 4 * quad + r;
      const float v = o[dt][r] / l_run[r];
      Ctx[((size_t)(b * 2048 + row)) * 2048 + h * 128 + 16 * dt + lc] = f2bf(v);
    }
}

// ---------------------------------------------------------------------------
extern "C" void kernel_launch(void* const* d_in, const int* in_sizes, int n_in,
                              void* d_out, int out_size, void* d_ws, size_t ws_size,
                              hipStream_t stream) {
  const float* x  = (const float*)d_in[0];
  const float* Wq = (const float*)d_in[1];
  const float* Wk = (const float*)d_in[2];
  const float* Wv = (const float*)d_in[3];
  const float* Wo = (const float*)d_in[4];
  float* out = (float*)d_out;

  char* ws = (char*)d_ws;
  size_t off = 0;
  auto alloc = [&](size_t bytes) {
    char* p = ws + off;
    off += (bytes + 255) & ~(size_t)255;
    return p;
  };
  const size_t XE = (size_t)4096 * 2048;   // B*S x H elements
  const size_t WE = (size_t)2048 * 2048;

  u16* xh  = (u16*)alloc(XE * 2);
  u16* xl  = (u16*)alloc(XE * 2);
  u16* Wqh = (u16*)alloc(WE * 2);
  u16* Wql = (u16*)alloc(WE * 2);
  u16* Wkh = (u16*)alloc(WE * 2);
  u16* Wkl = (u16*)alloc(WE * 2);
  u16* Wvh = (u16*)alloc(WE * 2);
  u16* Woh = (u16*)alloc(WE * 2);
  u16* Qhb = (u16*)alloc(XE * 2);
  u16* Qlb = (u16*)alloc(XE * 2);
  u16* Khb = (u16*)alloc(XE * 2);
  u16* Klb = (u16*)alloc(XE * 2);
  u16* Vb  = (u16*)alloc(XE * 2);
  u16* Vtb = (u16*)alloc(XE * 2);
  u16* Ctxb = (u16*)alloc(XE * 2);
  float* cosT = (float*)alloc((size_t)2048 * 64 * 4);
  float* sinT = (float*)alloc((size_t)2048 * 64 * 4);
  (void)ws_size;  // requires ~203 MB of workspace
  (void)in_sizes; (void)n_in; (void)out_size;

  // 1) precision split + RoPE tables
  split_bf16<<<8192, 256, 0, stream>>>(x, xh, xl, (int)(XE / 4));
  split_bf16<<<4096, 256, 0, stream>>>(Wq, Wqh, Wql, (int)(WE / 4));
  split_bf16<<<4096, 256, 0, stream>>>(Wk, Wkh, Wkl, (int)(WE / 4));
  split_bf16<<<4096, 256, 0, stream>>>(Wv, Wvh, nullptr, (int)(WE / 4));
  split_bf16<<<4096, 256, 0, stream>>>(Wo, Woh, nullptr, (int)(WE / 4));
  rope_tab<<<512, 256, 0, stream>>>(cosT, sinT);

  // 2) projections: Q,K split-precision with fused RoPE; V plain bf16
  gemm_bt<3, 1, 1><<<dim3(16, 32), 256, 0, stream>>>(
      xh, xl, Wqh, Wql, nullptr, Qhb, Qlb, cosT, sinT,
      11.313708498984760f, 4096, 2048, 2048);
  gemm_bt<3, 1, 1><<<dim3(16, 32), 256, 0, stream>>>(
      xh, xl, Wkh, Wkl, nullptr, Khb, Klb, cosT, sinT,
      1.0f, 4096, 2048, 2048);
  gemm_bt<1, 2, 0><<<dim3(16, 32), 256, 0, stream>>>(
      xh, nullptr, Wvh, nullptr, nullptr, Vb, nullptr, nullptr, nullptr,
      1.0f, 4096, 2048, 2048);

  // 3) V -> V^T per head for contiguous PV B-fragments
  transpose_v<<<dim3(256, 16, 2), 256, 0, stream>>>(Vb, Vtb);

  // 4) causal flash attention
  attn<<<dim3(16, 16, 2), 512, 0, stream>>>(Qhb, Qlb, Khb, Klb, Vtb, Ctxb);

  // 5) output projection -> fp32 d_out
  gemm_bt<1, 0, 0><<<dim3(16, 32), 256, 0, stream>>>(
      Ctxb, nullptr, Woh, nullptr, out, nullptr, nullptr, nullptr, nullptr,
      1.0f, 4096, 2048, 2048);
}

// Round 4
// 669.959 us; speedup vs baseline: 1.4399x; 1.0408x over previous
//
#include <hip/hip_runtime.h>
#include <cmath>

// ============================================================================
// AutoregressiveGroupQuerySelfAttention  (B=2, S=2048, H=2048, nH=16, D=128)
//
// Round 4:
//  - attn: single-buffered kN=64 K-tiles, LDS 71.7 KB -> 2 blocks/CU
//    (R3's double buffer at 125 KB pinned 1 block/CU; barriers had no
//    partner to overlap with -> zero gain, m99/m100 failure mode).
//    VGPR prefetch kept. Complementary qt pairing (z ? x : 15-x) so each
//    CU's two resident blocks sum to a constant 34 k-iterations.
//  - GEMM/RoPE-fusion/split-precision pipeline unchanged from R3.
// ============================================================================

typedef unsigned short u16;
typedef __attribute__((ext_vector_type(4))) float  f32x4;
typedef __attribute__((ext_vector_type(4))) float  float4v;
typedef __attribute__((ext_vector_type(4))) unsigned short u16x4;
typedef __attribute__((ext_vector_type(8))) unsigned short u16x8;
typedef __attribute__((ext_vector_type(8))) short s16x8;

__device__ __forceinline__ u16 f2bf(float f) {
  unsigned u = __float_as_uint(f);
  u += 0x7FFFu + ((u >> 16) & 1u);            // RNE; inputs are finite
  return (u16)(u >> 16);
}
__device__ __forceinline__ float bf2f(u16 h) {
  return __uint_as_float(((unsigned)h) << 16);
}
__device__ __forceinline__ f32x4 MFMA(s16x8 a, s16x8 b, f32x4 c) {
  return __builtin_amdgcn_mfma_f32_16x16x32_bf16(a, b, c, 0, 0, 0);
}
// async global->LDS, 16B per lane; LDS dest = wave-uniform base + lane*16
__device__ __forceinline__ void gld16(const void* g, void* s) {
  __builtin_amdgcn_global_load_lds(
      (const __attribute__((address_space(1))) void*)g,
      (__attribute__((address_space(3))) void*)s, 16, 0, 0);
}

// ---------------------------------------------------------------------------
// fp32 -> bf16 hi (+ optional lo residual).  n4 = element count / 4.
// ---------------------------------------------------------------------------
__global__ void split_bf16(const float* __restrict__ src, u16* __restrict__ hi,
                           u16* __restrict__ lo, int n4) {
  int i = blockIdx.x * 256 + threadIdx.x;
  if (i >= n4) return;
  float4v v = ((const float4v*)src)[i];
  u16x4 hv, lv;
#pragma unroll
  for (int j = 0; j < 4; ++j) {
    float f = v[j];
    u16 h = f2bf(f);
    hv[j] = h;
    lv[j] = f2bf(f - bf2f(h));
  }
  ((u16x4*)hi)[i] = hv;
  if (lo) ((u16x4*)lo)[i] = lv;
}

// ---------------------------------------------------------------------------
// RoPE tables in fp64.
// ---------------------------------------------------------------------------
__global__ void rope_tab(float* __restrict__ cosT, float* __restrict__ sinT) {
  int idx = blockIdx.x * 256 + threadIdx.x;   // 2048*64
  int i = idx & 63, s = idx >> 6;
  double invf = pow(10000.0, -(double)i / 64.0);
  double ang = (double)s * invf;
  cosT[idx] = (float)cos(ang);
  sinT[idx] = (float)sin(ang);
}

// ---------------------------------------------------------------------------
// V (B,S,16*128) bf16  ->  Vt (B,16,128,S) bf16   (per-head transpose)
// ---------------------------------------------------------------------------
__global__ void transpose_v(const u16* __restrict__ Vb, u16* __restrict__ Vt) {
  __shared__ u16 tile[32][40];
  int st = blockIdx.x >> 2;
  int dt = blockIdx.x & 3;
  int h = blockIdx.y, b = blockIdx.z;
  int t = threadIdx.x;
  int r = t >> 3, c = (t & 7) * 4;
  const u16* src = Vb + ((size_t)(b * 2048 + st * 32 + r)) * 2048 + h * 128 + dt * 32 + c;
  *(u16x4*)&tile[r][c] = *(const u16x4*)src;
  __syncthreads();
  u16x4 o;
#pragma unroll
  for (int j = 0; j < 4; ++j) o[j] = tile[c + j][r];
  u16* dst = Vt + ((size_t)((b * 16 + h) * 128 + dt * 32 + r)) * 2048 + st * 32 + c;
  *(u16x4*)dst = o;
}

// ---------------------------------------------------------------------------
// GEMM  C(MxN) = A(MxK) * B(NxK)^T, bf16 inputs, fp32 accumulate.
// NTERM==3: split precision (hh+hl+lh).
// OMODE: 0 fp32, 1 bf16 hi/lo, 2 bf16.   ROPE: fuse rotation in epilogue.
// 128x128 tile, BK=32, 4 waves each 32(m) x 128(n): acc[2][8].
// Staging via global_load_lds (16B/lane), unpadded LDS [128][32].
// ---------------------------------------------------------------------------
template <int NTERM, int OMODE, int ROPE>
__global__ __launch_bounds__(256, 3)
void gemm_bt(const u16* __restrict__ Ah, const u16* __restrict__ Al,
             const u16* __restrict__ Bh, const u16* __restrict__ Bl,
             float* __restrict__ Cf, u16* __restrict__ Ch, u16* __restrict__ Cl,
             const float* __restrict__ cosT, const float* __restrict__ sinT,
             float scale, int M, int N, int K) {
  __shared__ u16 As[128 * 32];
  __shared__ u16 Bs[128 * 32];
  __shared__ u16 Asl[NTERM == 3 ? 128 * 32 : 8];
  __shared__ u16 Bsl[NTERM == 3 ? 128 * 32 : 8];
  const int bn = blockIdx.x, bm = blockIdx.y;
  const int t = threadIdx.x;
  const int w = t >> 6, lane = t & 63, quad = lane >> 4, lc = lane & 15;

  const f32x4 ZERO = {0.f, 0.f, 0.f, 0.f};
  f32x4 acc[2][8];
#pragma unroll
  for (int i = 0; i < 2; ++i)
#pragma unroll
    for (int j = 0; j < 8; ++j) acc[i][j] = ZERO;

  const int sr0 = (lane >> 2);
  const int sc0 = (lane & 3) * 8;
  const size_t arow0 = (size_t)bm * 128, brow0 = (size_t)bn * 128;

  for (int k0 = 0; k0 < K; k0 += 32) {
#pragma unroll
    for (int p = 0; p < 2; ++p) {
      const int ch = 2 * w + p;
      const int r = ch * 16 + sr0;
      const size_t ga = (arow0 + r) * (size_t)K + k0 + sc0;
      const size_t gb = (brow0 + r) * (size_t)K + k0 + sc0;
      const int ldso = ch * 512 + lane * 8;   // u16 index
      gld16(&Ah[ga], &As[ldso]);
      gld16(&Bh[gb], &Bs[ldso]);
      if constexpr (NTERM == 3) {
        gld16(&Al[ga], &Asl[ldso]);
        gld16(&Bl[gb], &Bsl[ldso]);
      }
    }
    __syncthreads();

    s16x8 ah[2], al[2];
#pragma unroll
    for (int i = 0; i < 2; ++i) {
      ah[i] = *(const s16x8*)&As[(32 * w + 16 * i + lc) * 32 + 8 * quad];
      if constexpr (NTERM == 3)
        al[i] = *(const s16x8*)&Asl[(32 * w + 16 * i + lc) * 32 + 8 * quad];
    }
#pragma unroll
    for (int j = 0; j < 8; ++j) {
      const s16x8 bh = *(const s16x8*)&Bs[(16 * j + lc) * 32 + 8 * quad];
      s16x8 bl;
      if constexpr (NTERM == 3)
        bl = *(const s16x8*)&Bsl[(16 * j + lc) * 32 + 8 * quad];
#pragma unroll
      for (int i = 0; i < 2; ++i) {
        acc[i][j] = MFMA(ah[i], bh, acc[i][j]);
        if constexpr (NTERM == 3) {
          acc[i][j] = MFMA(ah[i], bl, acc[i][j]);
          acc[i][j] = MFMA(al[i], bh, acc[i][j]);
        }
      }
    }
    __syncthreads();
  }

  // ---- epilogue ----
  if constexpr (ROPE) {
    // N-tile 128 == one head (bn*128 head-aligned). Pair cols d and d+64.
#pragma unroll
    for (int i = 0; i < 2; ++i)
#pragma unroll
      for (int r = 0; r < 4; ++r) {
        const int row = bm * 128 + 32 * w + 16 * i + 4 * quad + r;
        const int s = row & 2047;
#pragma unroll
        for (int j = 0; j < 4; ++j) {
          const int hd = 16 * j + lc;
          const float cs = cosT[s * 64 + hd], sn = sinT[s * 64 + hd];
          const float q1 = acc[i][j][r], q2 = acc[i][j + 4][r];
          const float o1 = (q1 * cs - q2 * sn) * scale;
          const float o2 = (q2 * cs + q1 * sn) * scale;
          const size_t p1 = (size_t)row * N + bn * 128 + hd;
          const u16 h1 = f2bf(o1);
          Ch[p1] = h1; Cl[p1] = f2bf(o1 - bf2f(h1));
          const u16 h2 = f2bf(o2);
          Ch[p1 + 64] = h2; Cl[p1 + 64] = f2bf(o2 - bf2f(h2));
        }
      }
  } else {
#pragma unroll
    for (int i = 0; i < 2; ++i)
#pragma unroll
      for (int j = 0; j < 8; ++j) {
        const int col = bn * 128 + 16 * j + lc;
#pragma unroll
        for (int r = 0; r < 4; ++r) {
          const int row = bm * 128 + 32 * w + 16 * i + 4 * quad + r;
          const float v = acc[i][j][r];
          if constexpr (OMODE == 0) {
            Cf[(size_t)row * N + col] = v;
          } else if constexpr (OMODE == 1) {
            const u16 hv = f2bf(v);
            Ch[(size_t)row * N + col] = hv;
            Cl[(size_t)row * N + col] = f2bf(v - bf2f(hv));
          } else {
            Ch[(size_t)row * N + col] = f2bf(v);
          }
        }
      }
  }
}

// ---------------------------------------------------------------------------
// Flash attention, causal. Q pre-scaled by sqrt(D) (folded into GEMM epilogue).
// grid (16 x, 16 heads, 2 batches), qt = z ? x : 15-x (complementary pairing:
// the two co-resident blocks on a CU sum to a constant 34 k-iterations).
// 512 threads = 8 waves; wave w owns q-rows 16w..16w+15. kN=64, single
// LDS buffer (71.7 KB -> 2 blocks/CU), VGPR prefetch of tile kt+1.
// ---------------------------------------------------------------------------
__global__ __launch_bounds__(512, 4)
void attn(const u16* __restrict__ Qh, const u16* __restrict__ Ql,
          const u16* __restrict__ Kh, const u16* __restrict__ Kl,
          const u16* __restrict__ Vt, u16* __restrict__ Ctx) {
  constexpr int LDK = 136;   // 64 k-rows x 128 d (+8 pad)
  constexpr int LDV = 72;    // 128 d-rows x 64 s (+8 pad)
  constexpr int LDP = 72;    // 128 q-rows x 64 k (+8 pad)
  __shared__ u16 Ksh[64 * LDK];
  __shared__ u16 Ksl[64 * LDK];
  __shared__ u16 Vts[128 * LDV];
  __shared__ u16 Ps[128 * LDP];

  const int qt = blockIdx.z ? (int)blockIdx.x : 15 - (int)blockIdx.x;
  const int h = blockIdx.y, b = blockIdx.z;
  const int t = threadIdx.x;
  const int w = t >> 6, lane = t & 63, quad = lane >> 4, lc = lane & 15;

  // Q fragments in registers (A-layout: A[m=lane&15][k=quad*8+j]).
  s16x8 qfh[4], qfl[4];
#pragma unroll
  for (int s = 0; s < 4; ++s) {
    const size_t g = ((size_t)(b * 2048 + qt * 128 + 16 * w + lc)) * 2048
                     + h * 128 + 32 * s + 8 * quad;
    qfh[s] = *(const s16x8*)&Qh[g];
    qfl[s] = *(const s16x8*)&Ql[g];
  }

  const f32x4 ZERO = {0.f, 0.f, 0.f, 0.f};
  float m_run[4], l_run[4];
  f32x4 o[8];
#pragma unroll
  for (int r = 0; r < 4; ++r) { m_run[r] = -3.0e38f; l_run[r] = 0.f; }
#pragma unroll
  for (int dt = 0; dt < 8; ++dt) o[dt] = ZERO;

  const u16* gKh0 = Kh + ((size_t)(b * 2048)) * 2048 + h * 128;
  const u16* gKl0 = Kl + ((size_t)(b * 2048)) * 2048 + h * 128;
  const u16* gV0  = Vt + ((size_t)((b * 16 + h) * 128)) * 2048;

  const int ktmax = 2 * qt + 1;
  // staging maps
  const int krow = t >> 3;          // 0..63   (K tile row = k index)
  const int kcol = (t & 7) * 8;     // + 64p   (d)
  const int vrow = t >> 2;          // 0..127  (V^T row = d)
  const int vcol = (t & 3) * 8;     // + 32p   (s_local)

  u16x8 pKh[2], pKl[2], pV[2];

  // ---- prefetch tile 0 into VGPRs ----
#pragma unroll
  for (int p = 0; p < 2; ++p) {
    pKh[p] = *(const u16x8*)&gKh0[(size_t)krow * 2048 + kcol + 64 * p];
    pKl[p] = *(const u16x8*)&gKl0[(size_t)krow * 2048 + kcol + 64 * p];
    pV[p]  = *(const u16x8*)&gV0[(size_t)vrow * 2048 + vcol + 32 * p];
  }

  for (int kt = 0; kt <= ktmax; ++kt) {
    // ---- commit prefetched tile to LDS ----
#pragma unroll
    for (int p = 0; p < 2; ++p) {
      *(u16x8*)&Ksh[krow * LDK + kcol + 64 * p] = pKh[p];
      *(u16x8*)&Ksl[krow * LDK + kcol + 64 * p] = pKl[p];
      *(u16x8*)&Vts[vrow * LDV + vcol + 32 * p] = pV[p];
    }
    __syncthreads();

    // ---- prefetch next tile (global latency overlaps compute) ----
    if (kt < ktmax) {
#pragma unroll
      for (int p = 0; p < 2; ++p) {
        pKh[p] = *(const u16x8*)&gKh0[(size_t)((kt + 1) * 64 + krow) * 2048 + kcol + 64 * p];
        pKl[p] = *(const u16x8*)&gKl0[(size_t)((kt + 1) * 64 + krow) * 2048 + kcol + 64 * p];
        pV[p]  = *(const u16x8*)&gV0[(size_t)vrow * 2048 + (kt + 1) * 64 + vcol + 32 * p];
      }
    }

    // wave fully above the causal frontier at this k-tile?
    const bool active = (qt * 128 + 16 * w + 15) >= kt * 64;
    if (active) {
      // ---- S = Q K^T, split precision ----
      f32x4 acc[4];
#pragma unroll
      for (int c8 = 0; c8 < 4; ++c8) acc[c8] = ZERO;
#pragma unroll
      for (int c8 = 0; c8 < 4; ++c8) {
#pragma unroll
        for (int s = 0; s < 4; ++s) {
          const s16x8 bh = *(const s16x8*)&Ksh[(16 * c8 + lc) * LDK + 32 * s + 8 * quad];
          const s16x8 bl = *(const s16x8*)&Ksl[(16 * c8 + lc) * LDK + 32 * s + 8 * quad];
          acc[c8] = MFMA(qfh[s], bh, acc[c8]);
          acc[c8] = MFMA(qfh[s], bl, acc[c8]);
          acc[c8] = MFMA(qfl[s], bh, acc[c8]);
        }
      }

      // ---- online softmax ----
      const bool diag = (kt >= 2 * qt);
      float pvv[4][4];
#pragma unroll
      for (int c8 = 0; c8 < 4; ++c8)
#pragma unroll
        for (int r = 0; r < 4; ++r) {
          float v = acc[c8][r];
          if (diag && (kt * 64 + 16 * c8 + lc) > (qt * 128 + 16 * w + 4 * quad + r))
            v = -3.0e38f;
          pvv[c8][r] = v;
        }
#pragma unroll
      for (int r = 0; r < 4; ++r) {
        float mx = fmaxf(fmaxf(pvv[0][r], pvv[1][r]), fmaxf(pvv[2][r], pvv[3][r]));
        mx = fmaxf(mx, __shfl_xor(mx, 1));
        mx = fmaxf(mx, __shfl_xor(mx, 2));
        mx = fmaxf(mx, __shfl_xor(mx, 4));
        mx = fmaxf(mx, __shfl_xor(mx, 8));
        const float mn = fmaxf(m_run[r], mx);
        const float al = __expf(m_run[r] - mn);
        m_run[r] = mn;
        float rs = 0.f;
#pragma unroll
        for (int c8 = 0; c8 < 4; ++c8) {
          const float e = __expf(pvv[c8][r] - mn);
          pvv[c8][r] = e;
          rs += e;
        }
        rs += __shfl_xor(rs, 1);
        rs += __shfl_xor(rs, 2);
        rs += __shfl_xor(rs, 4);
        rs += __shfl_xor(rs, 8);
        l_run[r] = l_run[r] * al + rs;
#pragma unroll
        for (int dt = 0; dt < 8; ++dt) o[dt][r] *= al;
      }
      // pack P (bf16, unnormalized) -> Ps[qrow][kcol]; own rows only
#pragma unroll
      for (int c8 = 0; c8 < 4; ++c8)
#pragma unroll
        for (int r = 0; r < 4; ++r)
          Ps[(16 * w + 4 * quad + r) * LDP + 16 * c8 + lc] = f2bf(pvv[c8][r]);

      // ---- O += P * V ----
#pragma unroll
      for (int s = 0; s < 2; ++s) {
        const s16x8 af = *(const s16x8*)&Ps[(16 * w + lc) * LDP + 32 * s + 8 * quad];
#pragma unroll
        for (int dt = 0; dt < 8; ++dt) {
          const s16x8 bv = *(const s16x8*)&Vts[(16 * dt + lc) * LDV + 32 * s + 8 * quad];
          o[dt] = MFMA(af, bv, o[dt]);
        }
      }
    }
    __syncthreads();   // protect K/V/P tiles before next commit
  }

  // ---- normalize + store bf16 ctx (B,S,H) ----
#pragma unroll
  for (int dt = 0; dt < 8; ++dt)
#pragma unroll
    for (int r = 0; r < 4; ++r) {
      const int row = qt * 128 + 16 * w + 4 * quad + r;
      const float v = o[dt][r] / l_run[r];
      Ctx[((size_t)(b * 2048 + row)) * 2048 + h * 128 + 16 * dt + lc] = f2bf(v);
    }
}

// ---------------------------------------------------------------------------
extern "C" void kernel_launch(void* const* d_in, const int* in_sizes, int n_in,
                              void* d_out, int out_size, void* d_ws, size_t ws_size,
                              hipStream_t stream) {
  const float* x  = (const float*)d_in[0];
  const float* Wq = (const float*)d_in[1];
  const float* Wk = (const float*)d_in[2];
  const float* Wv = (const float*)d_in[3];
  const float* Wo = (const float*)d_in[4];
  float* out = (float*)d_out;

  char* ws = (char*)d_ws;
  size_t off = 0;
  auto alloc = [&](size_t bytes) {
    char* p = ws + off;
    off += (bytes + 255) & ~(size_t)255;
    return p;
  };
  const size_t XE = (size_t)4096 * 2048;   // B*S x H elements
  const size_t WE = (size_t)2048 * 2048;

  u16* xh  = (u16*)alloc(XE * 2);
  u16* xl  = (u16*)alloc(XE * 2);
  u16* Wqh = (u16*)alloc(WE * 2);
  u16* Wql = (u16*)alloc(WE * 2);
  u16* Wkh = (u16*)alloc(WE * 2);
  u16* Wkl = (u16*)alloc(WE * 2);
  u16* Wvh = (u16*)alloc(WE * 2);
  u16* Woh = (u16*)alloc(WE * 2);
  u16* Qhb = (u16*)alloc(XE * 2);
  u16* Qlb = (u16*)alloc(XE * 2);
  u16* Khb = (u16*)alloc(XE * 2);
  u16* Klb = (u16*)alloc(XE * 2);
  u16* Vb  = (u16*)alloc(XE * 2);
  u16* Vtb = (u16*)alloc(XE * 2);
  u16* Ctxb = (u16*)alloc(XE * 2);
  float* cosT = (float*)alloc((size_t)2048 * 64 * 4);
  float* sinT = (float*)alloc((size_t)2048 * 64 * 4);
  (void)ws_size;  // requires ~203 MB of workspace
  (void)in_sizes; (void)n_in; (void)out_size;

  // 1) precision split + RoPE tables
  split_bf16<<<8192, 256, 0, stream>>>(x, xh, xl, (int)(XE / 4));
  split_bf16<<<4096, 256, 0, stream>>>(Wq, Wqh, Wql, (int)(WE / 4));
  split_bf16<<<4096, 256, 0, stream>>>(Wk, Wkh, Wkl, (int)(WE / 4));
  split_bf16<<<4096, 256, 0, stream>>>(Wv, Wvh, nullptr, (int)(WE / 4));
  split_bf16<<<4096, 256, 0, stream>>>(Wo, Woh, nullptr, (int)(WE / 4));
  rope_tab<<<512, 256, 0, stream>>>(cosT, sinT);

  // 2) projections: Q,K split-precision with fused RoPE; V plain bf16
  gemm_bt<3, 1, 1><<<dim3(16, 32), 256, 0, stream>>>(
      xh, xl, Wqh, Wql, nullptr, Qhb, Qlb, cosT, sinT,
      11.313708498984760f, 4096, 2048, 2048);
  gemm_bt<3, 1, 1><<<dim3(16, 32), 256, 0, stream>>>(
      xh, xl, Wkh, Wkl, nullptr, Khb, Klb, cosT, sinT,
      1.0f, 4096, 2048, 2048);
  gemm_bt<1, 2, 0><<<dim3(16, 32), 256, 0, stream>>>(
      xh, nullptr, Wvh, nullptr, nullptr, Vb, nullptr, nullptr, nullptr,
      1.0f, 4096, 2048, 2048);

  // 3) V -> V^T per head for contiguous PV B-fragments
  transpose_v<<<dim3(256, 16, 2), 256, 0, stream>>>(Vb, Vtb);

  // 4) causal flash attention
  attn<<<dim3(16, 16, 2), 512, 0, stream>>>(Qhb, Qlb, Khb, Klb, Vtb, Ctxb);

  // 5) output projection -> fp32 d_out
  gemm_bt<1, 0, 0><<<dim3(16, 32), 256, 0, stream>>>(
      Ctxb, nullptr, Woh, nullptr, out, nullptr, nullptr, nullptr, nullptr,
      1.0f, 4096, 2048, 2048);
}

// Round 5
// 658.890 us; speedup vs baseline: 1.4641x; 1.0168x over previous
//
#include <hip/hip_runtime.h>
#include <cmath>

// ============================================================================
// AutoregressiveGroupQuerySelfAttention  (B=2, S=2048, H=2048, nH=16, D=128)
//
// Round 5:
//  - attn: launch_bounds back to (512,2). R4's (512,4) capped unified VGPRs
//    at 128 -> compiler spilled (VGPR_Count 64, WRITE_SIZE 16->219 MB,
//    FETCH +84 MB = ~300 MB scratch traffic). 96-VGPR allocation still fits
//    2 blocks/CU (LDS 71.7 KB is the limiter). Single-buffer kN=64 + VGPR
//    prefetch + complementary qt pairing kept.
//  - V^T computed directly: Vt = Wv * x^T via gemm_bt (M=2048,N=4096);
//    transpose_v kernel and Vb intermediate deleted. attn V row-stride 4096.
//  - Logit path (x, Wq, Wk, QK^T) split precision bf16 hi+lo, 3-term MFMA;
//    RoPE fused into Q/K GEMM epilogues.
// ============================================================================

typedef unsigned short u16;
typedef __attribute__((ext_vector_type(4))) float  f32x4;
typedef __attribute__((ext_vector_type(4))) float  float4v;
typedef __attribute__((ext_vector_type(4))) unsigned short u16x4;
typedef __attribute__((ext_vector_type(8))) unsigned short u16x8;
typedef __attribute__((ext_vector_type(8))) short s16x8;

__device__ __forceinline__ u16 f2bf(float f) {
  unsigned u = __float_as_uint(f);
  u += 0x7FFFu + ((u >> 16) & 1u);            // RNE; inputs are finite
  return (u16)(u >> 16);
}
__device__ __forceinline__ float bf2f(u16 h) {
  return __uint_as_float(((unsigned)h) << 16);
}
__device__ __forceinline__ f32x4 MFMA(s16x8 a, s16x8 b, f32x4 c) {
  return __builtin_amdgcn_mfma_f32_16x16x32_bf16(a, b, c, 0, 0, 0);
}
// async global->LDS, 16B per lane; LDS dest = wave-uniform base + lane*16
__device__ __forceinline__ void gld16(const void* g, void* s) {
  __builtin_amdgcn_global_load_lds(
      (const __attribute__((address_space(1))) void*)g,
      (__attribute__((address_space(3))) void*)s, 16, 0, 0);
}

// ---------------------------------------------------------------------------
// fp32 -> bf16 hi (+ optional lo residual).  n4 = element count / 4.
// ---------------------------------------------------------------------------
__global__ void split_bf16(const float* __restrict__ src, u16* __restrict__ hi,
                           u16* __restrict__ lo, int n4) {
  int i = blockIdx.x * 256 + threadIdx.x;
  if (i >= n4) return;
  float4v v = ((const float4v*)src)[i];
  u16x4 hv, lv;
#pragma unroll
  for (int j = 0; j < 4; ++j) {
    float f = v[j];
    u16 h = f2bf(f);
    hv[j] = h;
    lv[j] = f2bf(f - bf2f(h));
  }
  ((u16x4*)hi)[i] = hv;
  if (lo) ((u16x4*)lo)[i] = lv;
}

// ---------------------------------------------------------------------------
// RoPE tables in fp64.
// ---------------------------------------------------------------------------
__global__ void rope_tab(float* __restrict__ cosT, float* __restrict__ sinT) {
  int idx = blockIdx.x * 256 + threadIdx.x;   // 2048*64
  int i = idx & 63, s = idx >> 6;
  double invf = pow(10000.0, -(double)i / 64.0);
  double ang = (double)s * invf;
  cosT[idx] = (float)cos(ang);
  sinT[idx] = (float)sin(ang);
}

// ---------------------------------------------------------------------------
// GEMM  C(MxN) = A(MxK) * B(NxK)^T, bf16 inputs, fp32 accumulate.
// NTERM==3: split precision (hh+hl+lh).
// OMODE: 0 fp32, 1 bf16 hi/lo, 2 bf16.   ROPE: fuse rotation in epilogue.
// 128x128 tile, BK=32, 4 waves each 32(m) x 128(n): acc[2][8].
// Staging via global_load_lds (16B/lane), unpadded LDS [128][32].
// ---------------------------------------------------------------------------
template <int NTERM, int OMODE, int ROPE>
__global__ __launch_bounds__(256, 3)
void gemm_bt(const u16* __restrict__ Ah, const u16* __restrict__ Al,
             const u16* __restrict__ Bh, const u16* __restrict__ Bl,
             float* __restrict__ Cf, u16* __restrict__ Ch, u16* __restrict__ Cl,
             const float* __restrict__ cosT, const float* __restrict__ sinT,
             float scale, int M, int N, int K) {
  __shared__ u16 As[128 * 32];
  __shared__ u16 Bs[128 * 32];
  __shared__ u16 Asl[NTERM == 3 ? 128 * 32 : 8];
  __shared__ u16 Bsl[NTERM == 3 ? 128 * 32 : 8];
  const int bn = blockIdx.x, bm = blockIdx.y;
  const int t = threadIdx.x;
  const int w = t >> 6, lane = t & 63, quad = lane >> 4, lc = lane & 15;

  const f32x4 ZERO = {0.f, 0.f, 0.f, 0.f};
  f32x4 acc[2][8];
#pragma unroll
  for (int i = 0; i < 2; ++i)
#pragma unroll
    for (int j = 0; j < 8; ++j) acc[i][j] = ZERO;

  const int sr0 = (lane >> 2);
  const int sc0 = (lane & 3) * 8;
  const size_t arow0 = (size_t)bm * 128, brow0 = (size_t)bn * 128;

  for (int k0 = 0; k0 < K; k0 += 32) {
#pragma unroll
    for (int p = 0; p < 2; ++p) {
      const int ch = 2 * w + p;
      const int r = ch * 16 + sr0;
      const size_t ga = (arow0 + r) * (size_t)K + k0 + sc0;
      const size_t gb = (brow0 + r) * (size_t)K + k0 + sc0;
      const int ldso = ch * 512 + lane * 8;   // u16 index
      gld16(&Ah[ga], &As[ldso]);
      gld16(&Bh[gb], &Bs[ldso]);
      if constexpr (NTERM == 3) {
        gld16(&Al[ga], &Asl[ldso]);
        gld16(&Bl[gb], &Bsl[ldso]);
      }
    }
    __syncthreads();

    s16x8 ah[2], al[2];
#pragma unroll
    for (int i = 0; i < 2; ++i) {
      ah[i] = *(const s16x8*)&As[(32 * w + 16 * i + lc) * 32 + 8 * quad];
      if constexpr (NTERM == 3)
        al[i] = *(const s16x8*)&Asl[(32 * w + 16 * i + lc) * 32 + 8 * quad];
    }
#pragma unroll
    for (int j = 0; j < 8; ++j) {
      const s16x8 bh = *(const s16x8*)&Bs[(16 * j + lc) * 32 + 8 * quad];
      s16x8 bl;
      if constexpr (NTERM == 3)
        bl = *(const s16x8*)&Bsl[(16 * j + lc) * 32 + 8 * quad];
#pragma unroll
      for (int i = 0; i < 2; ++i) {
        acc[i][j] = MFMA(ah[i], bh, acc[i][j]);
        if constexpr (NTERM == 3) {
          acc[i][j] = MFMA(ah[i], bl, acc[i][j]);
          acc[i][j] = MFMA(al[i], bh, acc[i][j]);
        }
      }
    }
    __syncthreads();
  }

  // ---- epilogue ----
  if constexpr (ROPE) {
    // N-tile 128 == one head (bn*128 head-aligned). Pair cols d and d+64.
#pragma unroll
    for (int i = 0; i < 2; ++i)
#pragma unroll
      for (int r = 0; r < 4; ++r) {
        const int row = bm * 128 + 32 * w + 16 * i + 4 * quad + r;
        const int s = row & 2047;
#pragma unroll
        for (int j = 0; j < 4; ++j) {
          const int hd = 16 * j + lc;
          const float cs = cosT[s * 64 + hd], sn = sinT[s * 64 + hd];
          const float q1 = acc[i][j][r], q2 = acc[i][j + 4][r];
          const float o1 = (q1 * cs - q2 * sn) * scale;
          const float o2 = (q2 * cs + q1 * sn) * scale;
          const size_t p1 = (size_t)row * N + bn * 128 + hd;
          const u16 h1 = f2bf(o1);
          Ch[p1] = h1; Cl[p1] = f2bf(o1 - bf2f(h1));
          const u16 h2 = f2bf(o2);
          Ch[p1 + 64] = h2; Cl[p1 + 64] = f2bf(o2 - bf2f(h2));
        }
      }
  } else {
#pragma unroll
    for (int i = 0; i < 2; ++i)
#pragma unroll
      for (int j = 0; j < 8; ++j) {
        const int col = bn * 128 + 16 * j + lc;
#pragma unroll
        for (int r = 0; r < 4; ++r) {
          const int row = bm * 128 + 32 * w + 16 * i + 4 * quad + r;
          const float v = acc[i][j][r];
          if constexpr (OMODE == 0) {
            Cf[(size_t)row * N + col] = v;
          } else if constexpr (OMODE == 1) {
            const u16 hv = f2bf(v);
            Ch[(size_t)row * N + col] = hv;
            Cl[(size_t)row * N + col] = f2bf(v - bf2f(hv));
          } else {
            Ch[(size_t)row * N + col] = f2bf(v);
          }
        }
      }
  }
}

// ---------------------------------------------------------------------------
// Flash attention, causal. Q pre-scaled by sqrt(D) (folded into GEMM epilogue).
// grid (16 x, 16 heads, 2 batches), qt = z ? x : 15-x (complementary pairing).
// 512 threads = 8 waves; wave w owns q-rows 16w..16w+15. kN=64, single
// LDS buffer (71.7 KB -> 2 blocks/CU), VGPR prefetch of tile kt+1.
// V^T layout: Vt[dim=h*128+d][b*2048+s], row stride 4096.
// launch_bounds (512,2): budget 256 VGPR -> ~96 used, NO spill (R4's (512,4)
// capped at 128 and spilled 300 MB of scratch traffic).
// ---------------------------------------------------------------------------
__global__ __launch_bounds__(512, 2)
void attn(const u16* __restrict__ Qh, const u16* __restrict__ Ql,
          const u16* __restrict__ Kh, const u16* __restrict__ Kl,
          const u16* __restrict__ Vt, u16* __restrict__ Ctx) {
  constexpr int LDK = 136;   // 64 k-rows x 128 d (+8 pad)
  constexpr int LDV = 72;    // 128 d-rows x 64 s (+8 pad)
  constexpr int LDP = 72;    // 128 q-rows x 64 k (+8 pad)
  __shared__ u16 Ksh[64 * LDK];
  __shared__ u16 Ksl[64 * LDK];
  __shared__ u16 Vts[128 * LDV];
  __shared__ u16 Ps[128 * LDP];

  const int qt = blockIdx.z ? (int)blockIdx.x : 15 - (int)blockIdx.x;
  const int h = blockIdx.y, b = blockIdx.z;
  const int t = threadIdx.x;
  const int w = t >> 6, lane = t & 63, quad = lane >> 4, lc = lane & 15;

  // Q fragments in registers (A-layout: A[m=lane&15][k=quad*8+j]).
  s16x8 qfh[4], qfl[4];
#pragma unroll
  for (int s = 0; s < 4; ++s) {
    const size_t g = ((size_t)(b * 2048 + qt * 128 + 16 * w + lc)) * 2048
                     + h * 128 + 32 * s + 8 * quad;
    qfh[s] = *(const s16x8*)&Qh[g];
    qfl[s] = *(const s16x8*)&Ql[g];
  }

  const f32x4 ZERO = {0.f, 0.f, 0.f, 0.f};
  float m_run[4], l_run[4];
  f32x4 o[8];
#pragma unroll
  for (int r = 0; r < 4; ++r) { m_run[r] = -3.0e38f; l_run[r] = 0.f; }
#pragma unroll
  for (int dt = 0; dt < 8; ++dt) o[dt] = ZERO;

  const u16* gKh0 = Kh + ((size_t)(b * 2048)) * 2048 + h * 128;
  const u16* gKl0 = Kl + ((size_t)(b * 2048)) * 2048 + h * 128;
  const u16* gV0  = Vt + (size_t)(h * 128) * 4096 + b * 2048;   // row stride 4096

  const int ktmax = 2 * qt + 1;
  // staging maps
  const int krow = t >> 3;          // 0..63   (K tile row = k index)
  const int kcol = (t & 7) * 8;     // + 64p   (d)
  const int vrow = t >> 2;          // 0..127  (V^T row = d)
  const int vcol = (t & 3) * 8;     // + 32p   (s_local)

  u16x8 pKh[2], pKl[2], pV[2];

  // ---- prefetch tile 0 into VGPRs ----
#pragma unroll
  for (int p = 0; p < 2; ++p) {
    pKh[p] = *(const u16x8*)&gKh0[(size_t)krow * 2048 + kcol + 64 * p];
    pKl[p] = *(const u16x8*)&gKl0[(size_t)krow * 2048 + kcol + 64 * p];
    pV[p]  = *(const u16x8*)&gV0[(size_t)vrow * 4096 + vcol + 32 * p];
  }

  for (int kt = 0; kt <= ktmax; ++kt) {
    // ---- commit prefetched tile to LDS ----
#pragma unroll
    for (int p = 0; p < 2; ++p) {
      *(u16x8*)&Ksh[krow * LDK + kcol + 64 * p] = pKh[p];
      *(u16x8*)&Ksl[krow * LDK + kcol + 64 * p] = pKl[p];
      *(u16x8*)&Vts[vrow * LDV + vcol + 32 * p] = pV[p];
    }
    __syncthreads();

    // ---- prefetch next tile (global latency overlaps compute) ----
    if (kt < ktmax) {
#pragma unroll
      for (int p = 0; p < 2; ++p) {
        pKh[p] = *(const u16x8*)&gKh0[(size_t)((kt + 1) * 64 + krow) * 2048 + kcol + 64 * p];
        pKl[p] = *(const u16x8*)&gKl0[(size_t)((kt + 1) * 64 + krow) * 2048 + kcol + 64 * p];
        pV[p]  = *(const u16x8*)&gV0[(size_t)vrow * 4096 + (kt + 1) * 64 + vcol + 32 * p];
      }
    }

    // wave fully above the causal frontier at this k-tile?
    const bool active = (qt * 128 + 16 * w + 15) >= kt * 64;
    if (active) {
      // ---- S = Q K^T, split precision ----
      f32x4 acc[4];
#pragma unroll
      for (int c8 = 0; c8 < 4; ++c8) acc[c8] = ZERO;
#pragma unroll
      for (int c8 = 0; c8 < 4; ++c8) {
#pragma unroll
        for (int s = 0; s < 4; ++s) {
          const s16x8 bh = *(const s16x8*)&Ksh[(16 * c8 + lc) * LDK + 32 * s + 8 * quad];
          const s16x8 bl = *(const s16x8*)&Ksl[(16 * c8 + lc) * LDK + 32 * s + 8 * quad];
          acc[c8] = MFMA(qfh[s], bh, acc[c8]);
          acc[c8] = MFMA(qfh[s], bl, acc[c8]);
          acc[c8] = MFMA(qfl[s], bh, acc[c8]);
        }
      }

      // ---- online softmax ----
      const bool diag = (kt >= 2 * qt);
      float pvv[4][4];
#pragma unroll
      for (int c8 = 0; c8 < 4; ++c8)
#pragma unroll
        for (int r = 0; r < 4; ++r) {
          float v = acc[c8][r];
          if (diag && (kt * 64 + 16 * c8 + lc) > (qt * 128 + 16 * w + 4 * quad + r))
            v = -3.0e38f;
          pvv[c8][r] = v;
        }
#pragma unroll
      for (int r = 0; r < 4; ++r) {
        float mx = fmaxf(fmaxf(pvv[0][r], pvv[1][r]), fmaxf(pvv[2][r], pvv[3][r]));
        mx = fmaxf(mx, __shfl_xor(mx, 1));
        mx = fmaxf(mx, __shfl_xor(mx, 2));
        mx = fmaxf(mx, __shfl_xor(mx, 4));
        mx = fmaxf(mx, __shfl_xor(mx, 8));
        const float mn = fmaxf(m_run[r], mx);
        const float al = __expf(m_run[r] - mn);
        m_run[r] = mn;
        float rs = 0.f;
#pragma unroll
        for (int c8 = 0; c8 < 4; ++c8) {
          const float e = __expf(pvv[c8][r] - mn);
          pvv[c8][r] = e;
          rs += e;
        }
        rs += __shfl_xor(rs, 1);
        rs += __shfl_xor(rs, 2);
        rs += __shfl_xor(rs, 4);
        rs += __shfl_xor(rs, 8);
        l_run[r] = l_run[r] * al + rs;
#pragma unroll
        for (int dt = 0; dt < 8; ++dt) o[dt][r] *= al;
      }
      // pack P (bf16, unnormalized) -> Ps[qrow][kcol]; own rows only
#pragma unroll
      for (int c8 = 0; c8 < 4; ++c8)
#pragma unroll
        for (int r = 0; r < 4; ++r)
          Ps[(16 * w + 4 * quad + r) * LDP + 16 * c8 + lc] = f2bf(pvv[c8][r]);

      // ---- O += P * V ----
#pragma unroll
      for (int s = 0; s < 2; ++s) {
        const s16x8 af = *(const s16x8*)&Ps[(16 * w + lc) * LDP + 32 * s + 8 * quad];
#pragma unroll
        for (int dt = 0; dt < 8; ++dt) {
          const s16x8 bv = *(const s16x8*)&Vts[(16 * dt + lc) * LDV + 32 * s + 8 * quad];
          o[dt] = MFMA(af, bv, o[dt]);
        }
      }
    }
    __syncthreads();   // protect K/V/P tiles before next commit
  }

  // ---- normalize + store bf16 ctx (B,S,H) ----
#pragma unroll
  for (int dt = 0; dt < 8; ++dt)
#pragma unroll
    for (int r = 0; r < 4; ++r) {
      const int row = qt * 128 + 16 * w + 4 * quad + r;
      const float v = o[dt][r] / l_run[r];
      Ctx[((size_t)(b * 2048 + row)) * 2048 + h * 128 + 16 * dt + lc] = f2bf(v);
    }
}

// ---------------------------------------------------------------------------
extern "C" void kernel_launch(void* const* d_in, const int* in_sizes, int n_in,
                              void* d_out, int out_size, void* d_ws, size_t ws_size,
                              hipStream_t stream) {
  const float* x  = (const float*)d_in[0];
  const float* Wq = (const float*)d_in[1];
  const float* Wk = (const float*)d_in[2];
  const float* Wv = (const float*)d_in[3];
  const float* Wo = (const float*)d_in[4];
  float* out = (float*)d_out;

  char* ws = (char*)d_ws;
  size_t off = 0;
  auto alloc = [&](size_t bytes) {
    char* p = ws + off;
    off += (bytes + 255) & ~(size_t)255;
    return p;
  };
  const size_t XE = (size_t)4096 * 2048;   // B*S x H elements
  const size_t WE = (size_t)2048 * 2048;

  u16* xh  = (u16*)alloc(XE * 2);
  u16* xl  = (u16*)alloc(XE * 2);
  u16* Wqh = (u16*)alloc(WE * 2);
  u16* Wql = (u16*)alloc(WE * 2);
  u16* Wkh = (u16*)alloc(WE * 2);
  u16* Wkl = (u16*)alloc(WE * 2);
  u16* Wvh = (u16*)alloc(WE * 2);
  u16* Woh = (u16*)alloc(WE * 2);
  u16* Qhb = (u16*)alloc(XE * 2);
  u16* Qlb = (u16*)alloc(XE * 2);
  u16* Khb = (u16*)alloc(XE * 2);
  u16* Klb = (u16*)alloc(XE * 2);
  u16* Vtb = (u16*)alloc(XE * 2);   // V^T: [2048 dims][4096 seq]
  u16* Ctxb = (u16*)alloc(XE * 2);
  float* cosT = (float*)alloc((size_t)2048 * 64 * 4);
  float* sinT = (float*)alloc((size_t)2048 * 64 * 4);
  (void)ws_size;  // requires ~170 MB of workspace
  (void)in_sizes; (void)n_in; (void)out_size;

  // 1) precision split + RoPE tables
  split_bf16<<<8192, 256, 0, stream>>>(x, xh, xl, (int)(XE / 4));
  split_bf16<<<4096, 256, 0, stream>>>(Wq, Wqh, Wql, (int)(WE / 4));
  split_bf16<<<4096, 256, 0, stream>>>(Wk, Wkh, Wkl, (int)(WE / 4));
  split_bf16<<<4096, 256, 0, stream>>>(Wv, Wvh, nullptr, (int)(WE / 4));
  split_bf16<<<4096, 256, 0, stream>>>(Wo, Woh, nullptr, (int)(WE / 4));
  rope_tab<<<512, 256, 0, stream>>>(cosT, sinT);

  // 2) projections: Q,K split-precision with fused RoPE; V^T directly
  gemm_bt<3, 1, 1><<<dim3(16, 32), 256, 0, stream>>>(
      xh, xl, Wqh, Wql, nullptr, Qhb, Qlb, cosT, sinT,
      11.313708498984760f, 4096, 2048, 2048);
  gemm_bt<3, 1, 1><<<dim3(16, 32), 256, 0, stream>>>(
      xh, xl, Wkh, Wkl, nullptr, Khb, Klb, cosT, sinT,
      1.0f, 4096, 2048, 2048);
  // V^T = Wv * x^T :  A=Wv (M=2048 dims), B=x (N=4096 seq)
  gemm_bt<1, 2, 0><<<dim3(32, 16), 256, 0, stream>>>(
      Wvh, nullptr, xh, nullptr, nullptr, Vtb, nullptr, nullptr, nullptr,
      1.0f, 2048, 4096, 2048);

  // 3) causal flash attention
  attn<<<dim3(16, 16, 2), 512, 0, stream>>>(Qhb, Qlb, Khb, Klb, Vtb, Ctxb);

  // 4) output projection -> fp32 d_out
  gemm_bt<1, 0, 0><<<dim3(16, 32), 256, 0, stream>>>(
      Ctxb, nullptr, Woh, nullptr, out, nullptr, nullptr, nullptr, nullptr,
      1.0f, 4096, 2048, 2048);
}